// Round 7
// baseline (679.614 us; speedup 1.0000x reference)
//
#include <hip/hip_runtime.h>

namespace {

constexpr int Bn = 16;
constexpr int Nn = 2048;
constexpr int Dn = 512;

typedef _Float16 h4 __attribute__((ext_vector_type(4)));
typedef _Float16 h8 __attribute__((ext_vector_type(8)));
typedef float    fx4 __attribute__((ext_vector_type(4)));

__device__ __forceinline__ void gld16(const _Float16* g, _Float16* l) {
  typedef const void __attribute__((address_space(1))) gvoid;
  typedef void __attribute__((address_space(3))) lvoid;
  __builtin_amdgcn_global_load_lds((gvoid*)g, (lvoid*)l, 16, 0, 0);
}

// issue 2 x global_load_lds (16B) for a 128x32 f16 tile (linear LDS [128][32])
__device__ __forceinline__ void stage_gld(const _Float16* __restrict__ g, int ld,
    int r0, int k0, _Float16* __restrict__ lds, int t)
{
  #pragma unroll
  for (int i = 0; i < 2; ++i) {
    int chunk = i*256 + t;
    gld16(g + (long)(r0 + (chunk >> 2))*ld + k0 + (chunk & 3)*8, lds + chunk*8);
  }
}

// MODE 1 staging: f32 source -> regs
__device__ __forceinline__ void load_f32(const float* __restrict__ g, int ld,
    int r0, int k0, int t, fx4* regs)
{
  #pragma unroll
  for (int rd = 0; rd < 4; ++rd)
    regs[rd] = *(const fx4*)(g + (long)(r0 + rd*32 + (t >> 3))*ld + k0 + (t & 7)*4);
}
template<int S>
__device__ __forceinline__ void write_cvt(const fx4* regs, _Float16* __restrict__ lds, int t)
{
  const int c = (t & 7)*4;
  #pragma unroll
  for (int rd = 0; rd < 4; ++rd) {
    int r = rd*32 + (t >> 3);
    h4 o;
    #pragma unroll
    for (int i = 0; i < 4; ++i) o[i] = (_Float16)regs[rd][i];
    *(h4*)(lds + r*S + c) = o;
  }
}

// MODE 3 staging: f16 L source + exp(v - kofs[k]) -> f16
struct RegsA3 { h8 v0, v1; fx4 k00, k01, k10, k11; };
__device__ __forceinline__ void load_A3(const _Float16* __restrict__ g, int ld,
    int r0, int k0, int t, const float* __restrict__ kofs, RegsA3& R)
{
  {
    int chunk = t, r = chunk >> 2, c = (chunk & 3)*8;
    R.v0  = *(const h8*)(g + (long)(r0 + r)*ld + k0 + c);
    R.k00 = *(const fx4*)(kofs + k0 + c);
    R.k01 = *(const fx4*)(kofs + k0 + c + 4);
  }
  {
    int chunk = 256 + t, r = chunk >> 2, c = (chunk & 3)*8;
    R.v1  = *(const h8*)(g + (long)(r0 + r)*ld + k0 + c);
    R.k10 = *(const fx4*)(kofs + k0 + c);
    R.k11 = *(const fx4*)(kofs + k0 + c + 4);
  }
}
template<int S>
__device__ __forceinline__ void write_A3(const RegsA3& R, _Float16* __restrict__ lds, int t)
{
  {
    int chunk = t, r = chunk >> 2, c = (chunk & 3)*8;
    h8 o;
    #pragma unroll
    for (int j = 0; j < 4; ++j) {
      o[j]   = (_Float16)__expf((float)R.v0[j]   - R.k00[j]);
      o[4+j] = (_Float16)__expf((float)R.v0[4+j] - R.k01[j]);
    }
    *(h8*)(lds + r*S + c) = o;
  }
  {
    int chunk = 256 + t, r = chunk >> 2, c = (chunk & 3)*8;
    h8 o;
    #pragma unroll
    for (int j = 0; j < 4; ++j) {
      o[j]   = (_Float16)__expf((float)R.v1[j]   - R.k10[j]);
      o[4+j] = (_Float16)__expf((float)R.v1[4+j] - R.k11[j]);
    }
    *(h8*)(lds + r*S + c) = o;
  }
}

// ---------------- unified 128x128 double-buffered GEMM, XCD-chunked grid ----------------
// C[i][j] = sum_k A[i][k]*B[j][k]. 4 waves (2x2 of 64x64). BK=32, 2-phase pipeline.
// MA: 0 = f16 via global_load_lds, 1 = f32->f16 reg-staged, 3 = f16-L exp(v-kofs) reg-staged
// MB: 0 = f16 via global_load_lds, 1 = f32->f16 reg-staged
// EPI: 0 = f32 store; 1 = dual f16 store (C + C^T) + softmax partials; 2 = dual f16 store
// Grid: 1D, 16*TY tiles * 16 batches; 2 batches per XCD; by-fast tile order.
template<int MA, int MB, int EPI, int TY>
__global__ __launch_bounds__(256) void gemm128(
    const void* __restrict__ Ap, long sA,
    const void* __restrict__ Bp, long sB,
    void* __restrict__ Cp, long sC, int ldc,
    void* __restrict__ C2p, long sC2, int ldc2,
    int lda, int ldb, int K,
    const float* __restrict__ kofs,
    float* __restrict__ rowPM, float* __restrict__ rowPS,
    float* __restrict__ colPM, float* __restrict__ colPS)
{
  constexpr int SA = (MA == 0) ? 32 : 40;
  constexpr int SB = (MB == 0) ? 32 : 40;
  constexpr int ASZ = 128*SA, BSZ = 128*SB;
  constexpr int DB = 2*ASZ + 2*BSZ;
  constexpr int SMEM = (EPI >= 1 && DB < 128*136) ? 128*136 : DB;
  __shared__ _Float16 smem[SMEM];

  // XCD-chunked mapping: bid%8 = XCD; each XCD owns 2 consecutive batches
  constexpr int TILES = 16*TY;
  const int bid = blockIdx.x;
  const int xcd = bid & 7, slot = bid >> 3;
  const int b = xcd*2 + slot/TILES;
  const int tile = slot % TILES;
  const int by = tile % TY, bx = tile / TY;   // by-fast: B-panel reuse within XCD
  const int row0 = bx*128, col0 = by*128;

  const int t = threadIdx.x, w = t >> 6, l = t & 63;
  const int wr = w >> 1, wc = w & 1, l15 = l & 15, lg = l >> 4;

  const void* Ab;
  const void* Bb;
  if constexpr (MA == 1) Ab = (const void*)((const float*)Ap + (long)b*sA);
  else                   Ab = (const void*)((const _Float16*)Ap + (long)b*sA);
  if constexpr (MB == 1) Bb = (const void*)((const float*)Bp + (long)b*sB);
  else                   Bb = (const void*)((const _Float16*)Bp + (long)b*sB);

  const float* ko = nullptr;
  if constexpr (MA == 3) ko = kofs + (long)b*Nn;

  fx4 acc[4][4];
  #pragma unroll
  for (int fi = 0; fi < 4; ++fi)
    #pragma unroll
    for (int fj = 0; fj < 4; ++fj)
      acc[fi][fj] = (fx4){0.f, 0.f, 0.f, 0.f};

  const int NT = K/32;
  fx4 regA[4], regB[4];
  RegsA3 rA3;

  // prologue: tile 0 into buffer 0
  if constexpr (MA == 0)      stage_gld((const _Float16*)Ab, lda, row0, 0, smem, t);
  else if constexpr (MA == 1) load_f32((const float*)Ab, lda, row0, 0, t, regA);
  else                        load_A3((const _Float16*)Ab, lda, row0, 0, t, ko, rA3);
  if constexpr (MB == 0)      stage_gld((const _Float16*)Bb, ldb, col0, 0, smem + 2*ASZ, t);
  else                        load_f32((const float*)Bb, ldb, col0, 0, t, regB);
  if constexpr (MA == 1)      write_cvt<SA>(regA, smem, t);
  if constexpr (MA == 3)      write_A3<SA>(rA3, smem, t);
  if constexpr (MB == 1)      write_cvt<SB>(regB, smem + 2*ASZ, t);
  __syncthreads();

  for (int kt = 0; kt < NT; ++kt) {
    const int cur = kt & 1, nxt = cur ^ 1;
    const int k1 = (kt + 1)*32;
    _Float16* cA = smem + cur*ASZ;
    _Float16* cB = smem + 2*ASZ + cur*BSZ;
    _Float16* nA = smem + nxt*ASZ;
    _Float16* nB = smem + 2*ASZ + nxt*BSZ;

    if (kt + 1 < NT) {
      if constexpr (MA == 0)      stage_gld((const _Float16*)Ab, lda, row0, k1, nA, t);
      else if constexpr (MA == 1) load_f32((const float*)Ab, lda, row0, k1, t, regA);
      else                        load_A3((const _Float16*)Ab, lda, row0, k1, t, ko, rA3);
      if constexpr (MB == 0)      stage_gld((const _Float16*)Bb, ldb, col0, k1, nB, t);
      else                        load_f32((const float*)Bb, ldb, col0, k1, t, regB);
    }

    h8 af[4], bf[4];
    #pragma unroll
    for (int fi = 0; fi < 4; ++fi)
      af[fi] = *(const h8*)(cA + (wr*64 + fi*16 + l15)*SA + lg*8);
    #pragma unroll
    for (int fj = 0; fj < 4; ++fj)
      bf[fj] = *(const h8*)(cB + (wc*64 + fj*16 + l15)*SB + lg*8);
    #pragma unroll
    for (int fi = 0; fi < 4; ++fi)
      #pragma unroll
      for (int fj = 0; fj < 4; ++fj)
        acc[fi][fj] = __builtin_amdgcn_mfma_f32_16x16x32_f16(af[fi], bf[fj], acc[fi][fj], 0, 0, 0);

    if (kt + 1 < NT) {
      if constexpr (MA == 1) write_cvt<SA>(regA, nA, t);
      if constexpr (MA == 3) write_A3<SA>(rA3, nA, t);
      if constexpr (MB == 1) write_cvt<SB>(regB, nB, t);
    }
    __syncthreads();
  }

  if constexpr (EPI == 0) {
    float* Cb = (float*)Cp + (long)b*sC;
    #pragma unroll
    for (int fi = 0; fi < 4; ++fi)
      #pragma unroll
      for (int fj = 0; fj < 4; ++fj)
        #pragma unroll
        for (int j = 0; j < 4; ++j)
          Cb[(long)(row0 + wr*64 + fi*16 + lg*4 + j)*ldc + col0 + wc*64 + fj*16 + l15] = acc[fi][fj][j];
  }

  if constexpr (EPI == 1) {
    // round acc to f16 precision (stored Lh/Lt and the softmax stats stay consistent)
    #pragma unroll
    for (int fi = 0; fi < 4; ++fi)
      #pragma unroll
      for (int fj = 0; fj < 4; ++fj)
        #pragma unroll
        for (int j = 0; j < 4; ++j)
          acc[fi][fj][j] = (float)(_Float16)acc[fi][fj][j];

    // LDS image once; dual store: Lh row-major + Lt transposed
    #pragma unroll
    for (int fi = 0; fi < 4; ++fi)
      #pragma unroll
      for (int fj = 0; fj < 4; ++fj)
        #pragma unroll
        for (int j = 0; j < 4; ++j)
          smem[(wr*64 + fi*16 + lg*4 + j)*136 + wc*64 + fj*16 + l15] = (_Float16)acc[fi][fj][j];
    __syncthreads();
    _Float16* LhB = (_Float16*)Cp  + (long)b*sC;
    _Float16* LtB = (_Float16*)C2p + (long)b*sC2;
    #pragma unroll
    for (int rd = 0; rd < 8; ++rd) {
      int r = rd*16 + (t >> 4), c8 = (t & 15)*8;
      h8 v = *(const h8*)(smem + r*136 + c8);
      *(h8*)(LhB + (long)(row0 + r)*ldc + col0 + c8) = v;
    }
    #pragma unroll
    for (int rd = 0; rd < 8; ++rd) {
      int dl = rd*16 + (t >> 4), n8 = (t & 15)*8;
      h8 v;
      #pragma unroll
      for (int i = 0; i < 8; ++i) v[i] = smem[(n8 + i)*136 + dl];
      *(h8*)(LtB + (long)(col0 + dl)*ldc2 + row0 + n8) = v;
    }

    // row partials over this wave's 64-col half
    float rm[4][4], rs[4][4];
    #pragma unroll
    for (int fi = 0; fi < 4; ++fi)
      #pragma unroll
      for (int j = 0; j < 4; ++j)
        rm[fi][j] = fmaxf(fmaxf(acc[fi][0][j], acc[fi][1][j]),
                          fmaxf(acc[fi][2][j], acc[fi][3][j]));
    #pragma unroll
    for (int m = 1; m < 16; m <<= 1)
      #pragma unroll
      for (int fi = 0; fi < 4; ++fi)
        #pragma unroll
        for (int j = 0; j < 4; ++j)
          rm[fi][j] = fmaxf(rm[fi][j], __shfl_xor(rm[fi][j], m, 64));
    #pragma unroll
    for (int fi = 0; fi < 4; ++fi)
      #pragma unroll
      for (int j = 0; j < 4; ++j) {
        float s = 0.f;
        #pragma unroll
        for (int fj = 0; fj < 4; ++fj)
          s += __expf(acc[fi][fj][j] - rm[fi][j]);
        rs[fi][j] = s;
      }
    #pragma unroll
    for (int m = 1; m < 16; m <<= 1)
      #pragma unroll
      for (int fi = 0; fi < 4; ++fi)
        #pragma unroll
        for (int j = 0; j < 4; ++j)
          rs[fi][j] += __shfl_xor(rs[fi][j], m, 64);
    if (l15 == 0) {
      #pragma unroll
      for (int fi = 0; fi < 4; ++fi)
        #pragma unroll
        for (int j = 0; j < 4; ++j) {
          int row = row0 + wr*64 + fi*16 + lg*4 + j;
          long idx = ((long)b*Nn + row)*32 + by*2 + wc;
          rowPM[idx] = rm[fi][j];
          rowPS[idx] = rs[fi][j];
        }
    }
    // col partials over this wave's 64-row half
    float cm[4], cs[4];
    #pragma unroll
    for (int fj = 0; fj < 4; ++fj) {
      float v = -3.4e38f;
      #pragma unroll
      for (int fi = 0; fi < 4; ++fi)
        #pragma unroll
        for (int j = 0; j < 4; ++j)
          v = fmaxf(v, acc[fi][fj][j]);
      cm[fj] = v;
    }
    #pragma unroll
    for (int fj = 0; fj < 4; ++fj) {
      cm[fj] = fmaxf(cm[fj], __shfl_xor(cm[fj], 16, 64));
      cm[fj] = fmaxf(cm[fj], __shfl_xor(cm[fj], 32, 64));
    }
    #pragma unroll
    for (int fj = 0; fj < 4; ++fj) {
      float s = 0.f;
      #pragma unroll
      for (int fi = 0; fi < 4; ++fi)
        #pragma unroll
        for (int j = 0; j < 4; ++j)
          s += __expf(acc[fi][fj][j] - cm[fj]);
      cs[fj] = s;
    }
    #pragma unroll
    for (int fj = 0; fj < 4; ++fj) {
      cs[fj] += __shfl_xor(cs[fj], 16, 64);
      cs[fj] += __shfl_xor(cs[fj], 32, 64);
    }
    if (l < 16) {
      #pragma unroll
      for (int fj = 0; fj < 4; ++fj) {
        int col = col0 + wc*64 + fj*16 + l15;
        long idx = ((long)b*Nn + col)*32 + bx*2 + wr;
        colPM[idx] = cm[fj];
        colPS[idx] = cs[fj];
      }
    }
  }

  if constexpr (EPI == 2) {
    // dual f16 store via LDS transpose
    #pragma unroll
    for (int fi = 0; fi < 4; ++fi)
      #pragma unroll
      for (int fj = 0; fj < 4; ++fj)
        #pragma unroll
        for (int j = 0; j < 4; ++j)
          smem[(wr*64 + fi*16 + lg*4 + j)*136 + wc*64 + fj*16 + l15] = (_Float16)acc[fi][fj][j];
    __syncthreads();
    _Float16* Qb  = (_Float16*)Cp  + (long)b*sC;
    _Float16* QTb = (_Float16*)C2p + (long)b*sC2;
    #pragma unroll
    for (int rd = 0; rd < 8; ++rd) {
      int r = rd*16 + (t >> 4), c8 = (t & 15)*8;
      h8 v = *(const h8*)(smem + r*136 + c8);
      *(h8*)(Qb + (long)(row0 + r)*ldc + col0 + c8) = v;
    }
    #pragma unroll
    for (int rd = 0; rd < 8; ++rd) {
      int dl = rd*16 + (t >> 4), n8 = (t & 15)*8;
      h8 v;
      #pragma unroll
      for (int i = 0; i < 8; ++i) v[i] = smem[(n8 + i)*136 + dl];
      *(h8*)(QTb + (long)(col0 + dl)*ldc2 + row0 + n8) = v;
    }
  }
}

// ---------------- x2 f32 -> x2h f16 + x2hT f16 ----------------
__global__ __launch_bounds__(256) void convert_x2(const float* __restrict__ x2,
    _Float16* __restrict__ x2h, _Float16* __restrict__ x2hT)
{
  __shared__ _Float16 lt[64*66];
  const int b = blockIdx.z, m0 = blockIdx.x*64, d0 = blockIdx.y*64;
  const int t = threadIdx.x;
  const float* xb = x2 + (long)b*Nn*Dn;
  _Float16* hb = x2h + (long)b*Nn*Dn;
  #pragma unroll
  for (int rd = 0; rd < 4; ++rd) {
    int r = rd*16 + (t >> 4), c = (t & 15)*4;
    fx4 v = *(const fx4*)(xb + (long)(m0 + r)*Dn + d0 + c);
    h4 h;
    #pragma unroll
    for (int i = 0; i < 4; ++i) { h[i] = (_Float16)v[i]; lt[r*66 + c + i] = h[i]; }
    *(h4*)(hb + (long)(m0 + r)*Dn + d0 + c) = h;
  }
  __syncthreads();
  _Float16* tb = x2hT + (long)b*Dn*Nn;
  #pragma unroll
  for (int rd = 0; rd < 4; ++rd) {
    int dl = rd*16 + (t >> 4), ml = (t & 15)*4;
    h4 h;
    #pragma unroll
    for (int i = 0; i < 4; ++i) h[i] = lt[(ml + i)*66 + dl];
    *(h4*)(tb + (long)(d0 + dl)*Nn + m0 + ml) = h;
  }
}

// ---------------- combine 32 partials per row/col -> ofs = max + log(sum) ----------------
__global__ __launch_bounds__(256) void reduce_stats(
    const float* __restrict__ rowPM, const float* __restrict__ rowPS,
    const float* __restrict__ colPM, const float* __restrict__ colPS,
    float* __restrict__ rofs, float* __restrict__ cofs)
{
  const int w = threadIdx.x >> 6, l = threadIdx.x & 63;
  const long row = (long)blockIdx.x*4 + w;
  const float* PM = blockIdx.y ? colPM : rowPM;
  const float* PS = blockIdx.y ? colPS : rowPS;
  float m0 = PM[row*32 + (l & 31)];
  float s0 = PS[row*32 + (l & 31)];
  float m = m0;
  #pragma unroll
  for (int k = 1; k < 32; k <<= 1) m = fmaxf(m, __shfl_xor(m, k, 64));
  float v = s0 * __expf(m0 - m);
  #pragma unroll
  for (int k = 1; k < 32; k <<= 1) v += __shfl_xor(v, k, 64);
  if (l == 0) {
    float ofs = m + __logf(v);
    if (blockIdx.y == 0) rofs[row] = ofs;
    else                 cofs[row] = ofs;
  }
}

// ---------------- finalize_AQ: A_D[n][m] = exp(Lh-rofs[n]); A_Q[m][n] = exp(Lh-cofs[m]) ----
__global__ __launch_bounds__(256) void finalize_AQ(const _Float16* __restrict__ Lh,
    float* __restrict__ AD, float* __restrict__ AQ,
    const float* __restrict__ rofs, const float* __restrict__ cofs)
{
  __shared__ float l2[64*65];
  const int b = blockIdx.z, n0 = blockIdx.x*64, m0 = blockIdx.y*64;
  const int t = threadIdx.x;
  const _Float16* Lb = Lh + (long)b*Nn*Nn;
  float* Db = AD + (long)b*Nn*Nn;
  #pragma unroll
  for (int rd = 0; rd < 4; ++rd) {
    int r = rd*16 + (t >> 4), c = (t & 15)*4;
    h4 v = *(const h4*)(Lb + (long)(n0 + r)*Nn + m0 + c);
    float ro = rofs[(long)b*Nn + n0 + r];
    fx4 co = *(const fx4*)(cofs + (long)b*Nn + m0 + c);
    fx4 e1;
    #pragma unroll
    for (int i = 0; i < 4; ++i) {
      float lv = (float)v[i];
      e1[i] = __expf(lv - ro);
      l2[r*65 + c + i] = __expf(lv - co[i]);
    }
    *(fx4*)(Db + (long)(n0 + r)*Nn + m0 + c) = e1;
  }
  __syncthreads();
  float* Qb = AQ + (long)b*Nn*Nn;
  #pragma unroll
  for (int rd = 0; rd < 4; ++rd) {
    int ml = rd*16 + (t >> 4), nl = (t & 15)*4;
    fx4 q;
    #pragma unroll
    for (int i = 0; i < 4; ++i) q[i] = l2[(nl + i)*65 + ml];
    *(fx4*)(Qb + (long)(m0 + ml)*Nn + n0 + nl) = q;
  }
}

} // namespace

extern "C" void kernel_launch(void* const* d_in, const int* in_sizes, int n_in,
                              void* d_out, int out_size, void* d_ws, size_t ws_size,
                              hipStream_t stream)
{
  const float* x1 = (const float*)d_in[0];
  const float* x2 = (const float*)d_in[1];
  // d_in[2] = node_mask: unused by reference
  const float* Wq = (const float*)d_in[3];

  float* out = (float*)d_out;
  float* C_Q = out;
  float* C_D = out + (long)Bn*Nn*Dn;
  float* A_D = out + 2L*Bn*Nn*Dn;
  float* A_Q = A_D + (long)Bn*Nn*Nn;

  // ws: Qh, QhT, x2h, x2hT (f16) + Lh (f16) + stats
  char* ws = (char*)d_ws;
  _Float16* Qh   = (_Float16*)ws;
  _Float16* QhT  = Qh   + (long)Bn*Nn*Dn;
  _Float16* x2h  = QhT  + (long)Bn*Dn*Nn;
  _Float16* x2hT = x2h  + (long)Bn*Nn*Dn;
  _Float16* Lh   = x2hT + (long)Bn*Dn*Nn;
  float* rofs = (float*)(Lh + (long)Bn*Nn*Nn);
  float* cofs = rofs + (long)Bn*Nn;

  // scratch aliased into the A_Q output region (serialized: Lt+partials -> ... -> A_Q at K5b)
  _Float16* Lt = (_Float16*)A_Q;                                      // 134 MB
  float* rowPM = (float*)((char*)A_Q + sizeof(_Float16)*(long)Bn*Nn*Nn);
  float* rowPS = rowPM + (long)Bn*Nn*32;
  float* colPM = rowPS + (long)Bn*Nn*32;
  float* colPS = colPM + (long)Bn*Nn*32;

  dim3 blk(256);

  // K0: x2 -> f16 + transposed
  convert_x2<<<dim3(32, 8, 16), blk, 0, stream>>>(x2, x2h, x2hT);

  // K1: Q = x1 @ Wq^T -> Qh + QhT (f16). B = Wq shared across batches (sB = 0).
  gemm128<1,1,2,4><<<dim3(1024), blk, 0, stream>>>(
      x1, (long)Nn*Dn, Wq, 0L,
      Qh, (long)Nn*Dn, Dn, QhT, (long)Dn*Nn, Nn,
      Dn, Dn, Dn,
      nullptr, nullptr, nullptr, nullptr, nullptr);

  // K2: Lh + Lt = (f16)(Qh @ x2h^T) dual-store + fused softmax partials
  gemm128<0,0,1,16><<<dim3(4096), blk, 0, stream>>>(
      Qh, (long)Nn*Dn, x2h, (long)Nn*Dn,
      Lh, (long)Nn*Nn, Nn, Lt, (long)Nn*Nn, Nn,
      Dn, Dn, Dn,
      nullptr, rowPM, rowPS, colPM, colPS);

  // K3: combine partials -> rofs/cofs = max + log(sum)
  reduce_stats<<<dim3(Bn*Nn/4, 2), blk, 0, stream>>>(rowPM, rowPS, colPM, colPS, rofs, cofs);

  // K4: C_Q = colsoftmax(L) @ x2  (exp fused in A staging from f16 Lh)
  gemm128<3,0,0,4><<<dim3(1024), blk, 0, stream>>>(
      Lh, (long)Nn*Nn, x2hT, (long)Dn*Nn,
      C_Q, (long)Nn*Dn, Dn, nullptr, 0L, 0,
      Nn, Nn, Nn,
      cofs, nullptr, nullptr, nullptr, nullptr);

  // K6: C_D = rowsoftmax(L)^T @ Q  (exp fused in A staging from f16 Lt, kofs = rofs)
  gemm128<3,0,0,4><<<dim3(1024), blk, 0, stream>>>(
      Lt, (long)Nn*Nn, QhT, (long)Dn*Nn,
      C_D, (long)Nn*Dn, Dn, nullptr, 0L, 0,
      Nn, Nn, Nn,
      rofs, nullptr, nullptr, nullptr, nullptr);

  // K5b: A_D + A_Q outputs (A_Q overwrites Lt/partials scratch — runs after K6)
  finalize_AQ<<<dim3(32, 32, 16), blk, 0, stream>>>(Lh, A_D, A_Q, rofs, cofs);
}

// Round 8
// 632.074 us; speedup vs baseline: 1.0752x; 1.0752x over previous
//
#include <hip/hip_runtime.h>

namespace {

constexpr int Bn = 16;
constexpr int Nn = 2048;
constexpr int Dn = 512;

typedef _Float16 h4 __attribute__((ext_vector_type(4)));
typedef _Float16 h8 __attribute__((ext_vector_type(8)));
typedef float    fx4 __attribute__((ext_vector_type(4)));

__device__ __forceinline__ void gld16(const _Float16* g, _Float16* l) {
  typedef const void __attribute__((address_space(1))) gvoid;
  typedef void __attribute__((address_space(3))) lvoid;
  __builtin_amdgcn_global_load_lds((gvoid*)g, (lvoid*)l, 16, 0, 0);
}

// issue 2 x global_load_lds (16B) for a 128x32 f16 tile (linear LDS [128][32])
__device__ __forceinline__ void stage_gld(const _Float16* __restrict__ g, int ld,
    int r0, int k0, _Float16* __restrict__ lds, int t)
{
  #pragma unroll
  for (int i = 0; i < 2; ++i) {
    int chunk = i*256 + t;
    gld16(g + (long)(r0 + (chunk >> 2))*ld + k0 + (chunk & 3)*8, lds + chunk*8);
  }
}

// MODE 1 staging: f32 source -> regs
__device__ __forceinline__ void load_f32(const float* __restrict__ g, int ld,
    int r0, int k0, int t, fx4* regs)
{
  #pragma unroll
  for (int rd = 0; rd < 4; ++rd)
    regs[rd] = *(const fx4*)(g + (long)(r0 + rd*32 + (t >> 3))*ld + k0 + (t & 7)*4);
}
template<int S>
__device__ __forceinline__ void write_cvt(const fx4* regs, _Float16* __restrict__ lds, int t)
{
  const int c = (t & 7)*4;
  #pragma unroll
  for (int rd = 0; rd < 4; ++rd) {
    int r = rd*32 + (t >> 3);
    h4 o;
    #pragma unroll
    for (int i = 0; i < 4; ++i) o[i] = (_Float16)regs[rd][i];
    *(h4*)(lds + r*S + c) = o;
  }
}

// MODE 3 staging: f16 L source + exp(v - kofs[k]) -> f16
struct RegsA3 { h8 v0, v1; fx4 k00, k01, k10, k11; };
__device__ __forceinline__ void load_A3(const _Float16* __restrict__ g, int ld,
    int r0, int k0, int t, const float* __restrict__ kofs, RegsA3& R)
{
  {
    int chunk = t, r = chunk >> 2, c = (chunk & 3)*8;
    R.v0  = *(const h8*)(g + (long)(r0 + r)*ld + k0 + c);
    R.k00 = *(const fx4*)(kofs + k0 + c);
    R.k01 = *(const fx4*)(kofs + k0 + c + 4);
  }
  {
    int chunk = 256 + t, r = chunk >> 2, c = (chunk & 3)*8;
    R.v1  = *(const h8*)(g + (long)(r0 + r)*ld + k0 + c);
    R.k10 = *(const fx4*)(kofs + k0 + c);
    R.k11 = *(const fx4*)(kofs + k0 + c + 4);
  }
}
template<int S>
__device__ __forceinline__ void write_A3(const RegsA3& R, _Float16* __restrict__ lds, int t)
{
  {
    int chunk = t, r = chunk >> 2, c = (chunk & 3)*8;
    h8 o;
    #pragma unroll
    for (int j = 0; j < 4; ++j) {
      o[j]   = (_Float16)__expf((float)R.v0[j]   - R.k00[j]);
      o[4+j] = (_Float16)__expf((float)R.v0[4+j] - R.k01[j]);
    }
    *(h8*)(lds + r*S + c) = o;
  }
  {
    int chunk = 256 + t, r = chunk >> 2, c = (chunk & 3)*8;
    h8 o;
    #pragma unroll
    for (int j = 0; j < 4; ++j) {
      o[j]   = (_Float16)__expf((float)R.v1[j]   - R.k10[j]);
      o[4+j] = (_Float16)__expf((float)R.v1[4+j] - R.k11[j]);
    }
    *(h8*)(lds + r*S + c) = o;
  }
}

// ---------------- unified 128x128 double-buffered GEMM, XCD-chunked grid ----------------
// C[i][j] = sum_k A[i][k]*B[j][k]. 4 waves (2x2 of 64x64). BK=32, 2-phase pipeline.
// MA: 0 = f16 via global_load_lds, 1 = f32->f16 reg-staged, 3 = f16-L exp(v-kofs) reg-staged
// MB: 0 = f16 via global_load_lds, 1 = f32->f16 reg-staged
// EPI: 0 = f32 store; 1 = dual f16 store (C + C^T) + softmax partials; 2 = dual f16 store
// Epilogue C-image uses XOR-swizzled column groups: group' = (c>>3) ^ ((r>>3)&7).
// This makes the transposed gather (stride 8 rows = 544 dwords === 0 mod 32 banks)
// spread over 8 banks instead of 16-way single-bank conflicts.
// Grid: 1D, 16*TY tiles * 16 batches; 2 batches per XCD; by-fast tile order.
template<int MA, int MB, int EPI, int TY>
__global__ __launch_bounds__(256) void gemm128(
    const void* __restrict__ Ap, long sA,
    const void* __restrict__ Bp, long sB,
    void* __restrict__ Cp, long sC, int ldc,
    void* __restrict__ C2p, long sC2, int ldc2,
    int lda, int ldb, int K,
    const float* __restrict__ kofs,
    float* __restrict__ rowPM, float* __restrict__ rowPS,
    float* __restrict__ colPM, float* __restrict__ colPS)
{
  constexpr int SA = (MA == 0) ? 32 : 40;
  constexpr int SB = (MB == 0) ? 32 : 40;
  constexpr int ASZ = 128*SA, BSZ = 128*SB;
  constexpr int DB = 2*ASZ + 2*BSZ;
  constexpr int SMEM = (EPI >= 1 && DB < 128*136) ? 128*136 : DB;
  __shared__ _Float16 smem[SMEM];

  // XCD-chunked mapping: bid%8 = XCD; each XCD owns 2 consecutive batches
  constexpr int TILES = 16*TY;
  const int bid = blockIdx.x;
  const int xcd = bid & 7, slot = bid >> 3;
  const int b = xcd*2 + slot/TILES;
  const int tile = slot % TILES;
  const int by = tile % TY, bx = tile / TY;   // by-fast: B-panel reuse within XCD
  const int row0 = bx*128, col0 = by*128;

  const int t = threadIdx.x, w = t >> 6, l = t & 63;
  const int wr = w >> 1, wc = w & 1, l15 = l & 15, lg = l >> 4;

  const void* Ab;
  const void* Bb;
  if constexpr (MA == 1) Ab = (const void*)((const float*)Ap + (long)b*sA);
  else                   Ab = (const void*)((const _Float16*)Ap + (long)b*sA);
  if constexpr (MB == 1) Bb = (const void*)((const float*)Bp + (long)b*sB);
  else                   Bb = (const void*)((const _Float16*)Bp + (long)b*sB);

  const float* ko = nullptr;
  if constexpr (MA == 3) ko = kofs + (long)b*Nn;

  fx4 acc[4][4];
  #pragma unroll
  for (int fi = 0; fi < 4; ++fi)
    #pragma unroll
    for (int fj = 0; fj < 4; ++fj)
      acc[fi][fj] = (fx4){0.f, 0.f, 0.f, 0.f};

  const int NT = K/32;
  fx4 regA[4], regB[4];
  RegsA3 rA3;

  // prologue: tile 0 into buffer 0
  if constexpr (MA == 0)      stage_gld((const _Float16*)Ab, lda, row0, 0, smem, t);
  else if constexpr (MA == 1) load_f32((const float*)Ab, lda, row0, 0, t, regA);
  else                        load_A3((const _Float16*)Ab, lda, row0, 0, t, ko, rA3);
  if constexpr (MB == 0)      stage_gld((const _Float16*)Bb, ldb, col0, 0, smem + 2*ASZ, t);
  else                        load_f32((const float*)Bb, ldb, col0, 0, t, regB);
  if constexpr (MA == 1)      write_cvt<SA>(regA, smem, t);
  if constexpr (MA == 3)      write_A3<SA>(rA3, smem, t);
  if constexpr (MB == 1)      write_cvt<SB>(regB, smem + 2*ASZ, t);
  __syncthreads();

  for (int kt = 0; kt < NT; ++kt) {
    const int cur = kt & 1, nxt = cur ^ 1;
    const int k1 = (kt + 1)*32;
    _Float16* cA = smem + cur*ASZ;
    _Float16* cB = smem + 2*ASZ + cur*BSZ;
    _Float16* nA = smem + nxt*ASZ;
    _Float16* nB = smem + 2*ASZ + nxt*BSZ;

    if (kt + 1 < NT) {
      if constexpr (MA == 0)      stage_gld((const _Float16*)Ab, lda, row0, k1, nA, t);
      else if constexpr (MA == 1) load_f32((const float*)Ab, lda, row0, k1, t, regA);
      else                        load_A3((const _Float16*)Ab, lda, row0, k1, t, ko, rA3);
      if constexpr (MB == 0)      stage_gld((const _Float16*)Bb, ldb, col0, k1, nB, t);
      else                        load_f32((const float*)Bb, ldb, col0, k1, t, regB);
    }

    h8 af[4], bf[4];
    #pragma unroll
    for (int fi = 0; fi < 4; ++fi)
      af[fi] = *(const h8*)(cA + (wr*64 + fi*16 + l15)*SA + lg*8);
    #pragma unroll
    for (int fj = 0; fj < 4; ++fj)
      bf[fj] = *(const h8*)(cB + (wc*64 + fj*16 + l15)*SB + lg*8);
    #pragma unroll
    for (int fi = 0; fi < 4; ++fi)
      #pragma unroll
      for (int fj = 0; fj < 4; ++fj)
        acc[fi][fj] = __builtin_amdgcn_mfma_f32_16x16x32_f16(af[fi], bf[fj], acc[fi][fj], 0, 0, 0);

    if (kt + 1 < NT) {
      if constexpr (MA == 1) write_cvt<SA>(regA, nA, t);
      if constexpr (MA == 3) write_A3<SA>(rA3, nA, t);
      if constexpr (MB == 1) write_cvt<SB>(regB, nB, t);
    }
    __syncthreads();
  }

  if constexpr (EPI == 0) {
    float* Cb = (float*)Cp + (long)b*sC;
    #pragma unroll
    for (int fi = 0; fi < 4; ++fi)
      #pragma unroll
      for (int fj = 0; fj < 4; ++fj)
        #pragma unroll
        for (int j = 0; j < 4; ++j)
          Cb[(long)(row0 + wr*64 + fi*16 + lg*4 + j)*ldc + col0 + wc*64 + fj*16 + l15] = acc[fi][fj][j];
  }

  if constexpr (EPI >= 1) {
    if constexpr (EPI == 1) {
      // round acc to f16 precision (stored Lh/Lt and the softmax stats stay consistent)
      #pragma unroll
      for (int fi = 0; fi < 4; ++fi)
        #pragma unroll
        for (int fj = 0; fj < 4; ++fj)
          #pragma unroll
          for (int j = 0; j < 4; ++j)
            acc[fi][fj][j] = (float)(_Float16)acc[fi][fj][j];
    }

    // swizzled LDS image: (r,c) -> r*136 + (((c>>3) ^ ((r>>3)&7))<<3 | (c&7))
    #pragma unroll
    for (int fi = 0; fi < 4; ++fi) {
      #pragma unroll
      for (int j = 0; j < 4; ++j) {
        int rr = wr*64 + fi*16 + lg*4 + j;
        int key = (rr >> 3) & 7;
        #pragma unroll
        for (int fj = 0; fj < 4; ++fj) {
          int cc = wc*64 + fj*16 + l15;
          smem[rr*136 + ((((cc >> 3) ^ key) << 3) | (cc & 7))] = (_Float16)acc[fi][fj][j];
        }
      }
    }
    __syncthreads();
    _Float16* Cb  = (_Float16*)Cp  + (long)b*sC;
    _Float16* C2b = (_Float16*)C2p + (long)b*sC2;
    // row-major store: read swizzled group
    #pragma unroll
    for (int rd = 0; rd < 8; ++rd) {
      int r = rd*16 + (t >> 4);
      int g = (t & 15) ^ ((r >> 3) & 7);
      h8 v = *(const h8*)(smem + r*136 + g*8);
      *(h8*)(Cb + (long)(row0 + r)*ldc + col0 + (t & 15)*8) = v;
    }
    // transposed store: gather column dl over rows 8q..8q+7 (lane-static key = q&7)
    {
      const int q = t & 15, keyq = q & 7, n8 = q*8;
      #pragma unroll
      for (int rd = 0; rd < 8; ++rd) {
        int dl = rd*16 + (t >> 4);
        int gbase = ((dl >> 3) ^ keyq) << 3, c7 = dl & 7;
        h8 v;
        #pragma unroll
        for (int i = 0; i < 8; ++i)
          v[i] = smem[(n8 + i)*136 + gbase + c7];
        *(h8*)(C2b + (long)(col0 + dl)*ldc2 + row0 + n8) = v;
      }
    }
  }

  if constexpr (EPI == 1) {
    // row partials over this wave's 64-col half
    float rm[4][4], rs[4][4];
    #pragma unroll
    for (int fi = 0; fi < 4; ++fi)
      #pragma unroll
      for (int j = 0; j < 4; ++j)
        rm[fi][j] = fmaxf(fmaxf(acc[fi][0][j], acc[fi][1][j]),
                          fmaxf(acc[fi][2][j], acc[fi][3][j]));
    #pragma unroll
    for (int m = 1; m < 16; m <<= 1)
      #pragma unroll
      for (int fi = 0; fi < 4; ++fi)
        #pragma unroll
        for (int j = 0; j < 4; ++j)
          rm[fi][j] = fmaxf(rm[fi][j], __shfl_xor(rm[fi][j], m, 64));
    #pragma unroll
    for (int fi = 0; fi < 4; ++fi)
      #pragma unroll
      for (int j = 0; j < 4; ++j) {
        float s = 0.f;
        #pragma unroll
        for (int fj = 0; fj < 4; ++fj)
          s += __expf(acc[fi][fj][j] - rm[fi][j]);
        rs[fi][j] = s;
      }
    #pragma unroll
    for (int m = 1; m < 16; m <<= 1)
      #pragma unroll
      for (int fi = 0; fi < 4; ++fi)
        #pragma unroll
        for (int j = 0; j < 4; ++j)
          rs[fi][j] += __shfl_xor(rs[fi][j], m, 64);
    if (l15 == 0) {
      #pragma unroll
      for (int fi = 0; fi < 4; ++fi)
        #pragma unroll
        for (int j = 0; j < 4; ++j) {
          int row = row0 + wr*64 + fi*16 + lg*4 + j;
          long idx = ((long)b*Nn + row)*32 + by*2 + wc;
          rowPM[idx] = rm[fi][j];
          rowPS[idx] = rs[fi][j];
        }
    }
    // col partials over this wave's 64-row half
    float cm[4], cs[4];
    #pragma unroll
    for (int fj = 0; fj < 4; ++fj) {
      float v = -3.4e38f;
      #pragma unroll
      for (int fi = 0; fi < 4; ++fi)
        #pragma unroll
        for (int j = 0; j < 4; ++j)
          v = fmaxf(v, acc[fi][fj][j]);
      cm[fj] = v;
    }
    #pragma unroll
    for (int fj = 0; fj < 4; ++fj) {
      cm[fj] = fmaxf(cm[fj], __shfl_xor(cm[fj], 16, 64));
      cm[fj] = fmaxf(cm[fj], __shfl_xor(cm[fj], 32, 64));
    }
    #pragma unroll
    for (int fj = 0; fj < 4; ++fj) {
      float s = 0.f;
      #pragma unroll
      for (int fi = 0; fi < 4; ++fi)
        #pragma unroll
        for (int j = 0; j < 4; ++j)
          s += __expf(acc[fi][fj][j] - cm[fj]);
      cs[fj] = s;
    }
    #pragma unroll
    for (int fj = 0; fj < 4; ++fj) {
      cs[fj] += __shfl_xor(cs[fj], 16, 64);
      cs[fj] += __shfl_xor(cs[fj], 32, 64);
    }
    if (l < 16) {
      #pragma unroll
      for (int fj = 0; fj < 4; ++fj) {
        int col = col0 + wc*64 + fj*16 + l15;
        long idx = ((long)b*Nn + col)*32 + bx*2 + wr;
        colPM[idx] = cm[fj];
        colPS[idx] = cs[fj];
      }
    }
  }
}

// ---------------- x2 f32 -> x2h f16 + x2hT f16 ----------------
__global__ __launch_bounds__(256) void convert_x2(const float* __restrict__ x2,
    _Float16* __restrict__ x2h, _Float16* __restrict__ x2hT)
{
  __shared__ _Float16 lt[64*66];
  const int b = blockIdx.z, m0 = blockIdx.x*64, d0 = blockIdx.y*64;
  const int t = threadIdx.x;
  const float* xb = x2 + (long)b*Nn*Dn;
  _Float16* hb = x2h + (long)b*Nn*Dn;
  #pragma unroll
  for (int rd = 0; rd < 4; ++rd) {
    int r = rd*16 + (t >> 4), c = (t & 15)*4;
    fx4 v = *(const fx4*)(xb + (long)(m0 + r)*Dn + d0 + c);
    h4 h;
    #pragma unroll
    for (int i = 0; i < 4; ++i) { h[i] = (_Float16)v[i]; lt[r*66 + c + i] = h[i]; }
    *(h4*)(hb + (long)(m0 + r)*Dn + d0 + c) = h;
  }
  __syncthreads();
  _Float16* tb = x2hT + (long)b*Dn*Nn;
  #pragma unroll
  for (int rd = 0; rd < 4; ++rd) {
    int dl = rd*16 + (t >> 4), ml = (t & 15)*4;
    h4 h;
    #pragma unroll
    for (int i = 0; i < 4; ++i) h[i] = lt[(ml + i)*66 + dl];
    *(h4*)(tb + (long)(d0 + dl)*Nn + m0 + ml) = h;
  }
}

// ---------------- combine 32 partials per row/col -> ofs = max + log(sum) ----------------
__global__ __launch_bounds__(256) void reduce_stats(
    const float* __restrict__ rowPM, const float* __restrict__ rowPS,
    const float* __restrict__ colPM, const float* __restrict__ colPS,
    float* __restrict__ rofs, float* __restrict__ cofs)
{
  const int w = threadIdx.x >> 6, l = threadIdx.x & 63;
  const long row = (long)blockIdx.x*4 + w;
  const float* PM = blockIdx.y ? colPM : rowPM;
  const float* PS = blockIdx.y ? colPS : rowPS;
  float m0 = PM[row*32 + (l & 31)];
  float s0 = PS[row*32 + (l & 31)];
  float m = m0;
  #pragma unroll
  for (int k = 1; k < 32; k <<= 1) m = fmaxf(m, __shfl_xor(m, k, 64));
  float v = s0 * __expf(m0 - m);
  #pragma unroll
  for (int k = 1; k < 32; k <<= 1) v += __shfl_xor(v, k, 64);
  if (l == 0) {
    float ofs = m + __logf(v);
    if (blockIdx.y == 0) rofs[row] = ofs;
    else                 cofs[row] = ofs;
  }
}

// ---------------- finalize_AQ: A_D[n][m] = exp(Lh-rofs[n]); A_Q[m][n] = exp(Lh-cofs[m]) ----
__global__ __launch_bounds__(256) void finalize_AQ(const _Float16* __restrict__ Lh,
    float* __restrict__ AD, float* __restrict__ AQ,
    const float* __restrict__ rofs, const float* __restrict__ cofs)
{
  __shared__ float l2[64*65];
  const int b = blockIdx.z, n0 = blockIdx.x*64, m0 = blockIdx.y*64;
  const int t = threadIdx.x;
  const _Float16* Lb = Lh + (long)b*Nn*Nn;
  float* Db = AD + (long)b*Nn*Nn;
  #pragma unroll
  for (int rd = 0; rd < 4; ++rd) {
    int r = rd*16 + (t >> 4), c = (t & 15)*4;
    h4 v = *(const h4*)(Lb + (long)(n0 + r)*Nn + m0 + c);
    float ro = rofs[(long)b*Nn + n0 + r];
    fx4 co = *(const fx4*)(cofs + (long)b*Nn + m0 + c);
    fx4 e1;
    #pragma unroll
    for (int i = 0; i < 4; ++i) {
      float lv = (float)v[i];
      e1[i] = __expf(lv - ro);
      l2[r*65 + c + i] = __expf(lv - co[i]);
    }
    *(fx4*)(Db + (long)(n0 + r)*Nn + m0 + c) = e1;
  }
  __syncthreads();
  float* Qb = AQ + (long)b*Nn*Nn;
  #pragma unroll
  for (int rd = 0; rd < 4; ++rd) {
    int ml = rd*16 + (t >> 4), nl = (t & 15)*4;
    fx4 q;
    #pragma unroll
    for (int i = 0; i < 4; ++i) q[i] = l2[(nl + i)*65 + ml];
    *(fx4*)(Qb + (long)(m0 + ml)*Nn + n0 + nl) = q;
  }
}

} // namespace

extern "C" void kernel_launch(void* const* d_in, const int* in_sizes, int n_in,
                              void* d_out, int out_size, void* d_ws, size_t ws_size,
                              hipStream_t stream)
{
  const float* x1 = (const float*)d_in[0];
  const float* x2 = (const float*)d_in[1];
  // d_in[2] = node_mask: unused by reference
  const float* Wq = (const float*)d_in[3];

  float* out = (float*)d_out;
  float* C_Q = out;
  float* C_D = out + (long)Bn*Nn*Dn;
  float* A_D = out + 2L*Bn*Nn*Dn;
  float* A_Q = A_D + (long)Bn*Nn*Nn;

  // ws: Qh, QhT, x2h, x2hT (f16) + Lh (f16) + stats
  char* ws = (char*)d_ws;
  _Float16* Qh   = (_Float16*)ws;
  _Float16* QhT  = Qh   + (long)Bn*Nn*Dn;
  _Float16* x2h  = QhT  + (long)Bn*Dn*Nn;
  _Float16* x2hT = x2h  + (long)Bn*Nn*Dn;
  _Float16* Lh   = x2hT + (long)Bn*Dn*Nn;
  float* rofs = (float*)(Lh + (long)Bn*Nn*Nn);
  float* cofs = rofs + (long)Bn*Nn;

  // scratch aliased into the A_Q output region (serialized: Lt+partials -> ... -> A_Q at K5b)
  _Float16* Lt = (_Float16*)A_Q;                                      // 134 MB
  float* rowPM = (float*)((char*)A_Q + sizeof(_Float16)*(long)Bn*Nn*Nn);
  float* rowPS = rowPM + (long)Bn*Nn*32;
  float* colPM = rowPS + (long)Bn*Nn*32;
  float* colPS = colPM + (long)Bn*Nn*32;

  dim3 blk(256);

  // K0: x2 -> f16 + transposed
  convert_x2<<<dim3(32, 8, 16), blk, 0, stream>>>(x2, x2h, x2hT);

  // K1: Q = x1 @ Wq^T -> Qh + QhT (f16). B = Wq shared across batches (sB = 0).
  gemm128<1,1,2,4><<<dim3(1024), blk, 0, stream>>>(
      x1, (long)Nn*Dn, Wq, 0L,
      Qh, (long)Nn*Dn, Dn, QhT, (long)Dn*Nn, Nn,
      Dn, Dn, Dn,
      nullptr, nullptr, nullptr, nullptr, nullptr);

  // K2: Lh + Lt = (f16)(Qh @ x2h^T) dual-store + fused softmax partials
  gemm128<0,0,1,16><<<dim3(4096), blk, 0, stream>>>(
      Qh, (long)Nn*Dn, x2h, (long)Nn*Dn,
      Lh, (long)Nn*Nn, Nn, Lt, (long)Nn*Nn, Nn,
      Dn, Dn, Dn,
      nullptr, rowPM, rowPS, colPM, colPS);

  // K3: combine partials -> rofs/cofs = max + log(sum)
  reduce_stats<<<dim3(Bn*Nn/4, 2), blk, 0, stream>>>(rowPM, rowPS, colPM, colPS, rofs, cofs);

  // K4: C_Q = colsoftmax(L) @ x2  (exp fused in A staging from f16 Lh)
  gemm128<3,0,0,4><<<dim3(1024), blk, 0, stream>>>(
      Lh, (long)Nn*Nn, x2hT, (long)Dn*Nn,
      C_Q, (long)Nn*Dn, Dn, nullptr, 0L, 0,
      Nn, Nn, Nn,
      cofs, nullptr, nullptr, nullptr, nullptr);

  // K6: C_D = rowsoftmax(L)^T @ Q  (exp fused in A staging from f16 Lt, kofs = rofs)
  gemm128<3,0,0,4><<<dim3(1024), blk, 0, stream>>>(
      Lt, (long)Nn*Nn, QhT, (long)Dn*Nn,
      C_D, (long)Nn*Dn, Dn, nullptr, 0L, 0,
      Nn, Nn, Nn,
      rofs, nullptr, nullptr, nullptr, nullptr);

  // K5b: A_D + A_Q outputs (A_Q overwrites Lt/partials scratch — runs after K6)
  finalize_AQ<<<dim3(32, 32, 16), blk, 0, stream>>>(Lh, A_D, A_Q, rofs, cofs);
}

// Round 9
// 629.610 us; speedup vs baseline: 1.0794x; 1.0039x over previous
//
#include <hip/hip_runtime.h>

namespace {

constexpr int Bn = 16;
constexpr int Nn = 2048;
constexpr int Dn = 512;

typedef _Float16 h4 __attribute__((ext_vector_type(4)));
typedef _Float16 h8 __attribute__((ext_vector_type(8)));
typedef float    fx4 __attribute__((ext_vector_type(4)));

__device__ __forceinline__ void gld16(const _Float16* g, _Float16* l) {
  typedef const void __attribute__((address_space(1))) gvoid;
  typedef void __attribute__((address_space(3))) lvoid;
  __builtin_amdgcn_global_load_lds((gvoid*)g, (lvoid*)l, 16, 0, 0);
}

// issue 2 x global_load_lds (16B) for a 128x32 f16 tile (linear LDS [128][32])
__device__ __forceinline__ void stage_gld(const _Float16* __restrict__ g, int ld,
    int r0, int k0, _Float16* __restrict__ lds, int t)
{
  #pragma unroll
  for (int i = 0; i < 2; ++i) {
    int chunk = i*256 + t;
    gld16(g + (long)(r0 + (chunk >> 2))*ld + k0 + (chunk & 3)*8, lds + chunk*8);
  }
}

// MODE 1 staging: f32 source -> regs
__device__ __forceinline__ void load_f32(const float* __restrict__ g, int ld,
    int r0, int k0, int t, fx4* regs)
{
  #pragma unroll
  for (int rd = 0; rd < 4; ++rd)
    regs[rd] = *(const fx4*)(g + (long)(r0 + rd*32 + (t >> 3))*ld + k0 + (t & 7)*4);
}
template<int S>
__device__ __forceinline__ void write_cvt(const fx4* regs, _Float16* __restrict__ lds, int t)
{
  const int c = (t & 7)*4;
  #pragma unroll
  for (int rd = 0; rd < 4; ++rd) {
    int r = rd*32 + (t >> 3);
    h4 o;
    #pragma unroll
    for (int i = 0; i < 4; ++i) o[i] = (_Float16)regs[rd][i];
    *(h4*)(lds + r*S + c) = o;
  }
}

// MODE 3 staging: f16 L source + exp(v - kofs[k]) -> f16
struct RegsA3 { h8 v0, v1; fx4 k00, k01, k10, k11; };
__device__ __forceinline__ void load_A3(const _Float16* __restrict__ g, int ld,
    int r0, int k0, int t, const float* __restrict__ kofs, RegsA3& R)
{
  {
    int chunk = t, r = chunk >> 2, c = (chunk & 3)*8;
    R.v0  = *(const h8*)(g + (long)(r0 + r)*ld + k0 + c);
    R.k00 = *(const fx4*)(kofs + k0 + c);
    R.k01 = *(const fx4*)(kofs + k0 + c + 4);
  }
  {
    int chunk = 256 + t, r = chunk >> 2, c = (chunk & 3)*8;
    R.v1  = *(const h8*)(g + (long)(r0 + r)*ld + k0 + c);
    R.k10 = *(const fx4*)(kofs + k0 + c);
    R.k11 = *(const fx4*)(kofs + k0 + c + 4);
  }
}
template<int S>
__device__ __forceinline__ void write_A3(const RegsA3& R, _Float16* __restrict__ lds, int t)
{
  {
    int chunk = t, r = chunk >> 2, c = (chunk & 3)*8;
    h8 o;
    #pragma unroll
    for (int j = 0; j < 4; ++j) {
      o[j]   = (_Float16)__expf((float)R.v0[j]   - R.k00[j]);
      o[4+j] = (_Float16)__expf((float)R.v0[4+j] - R.k01[j]);
    }
    *(h8*)(lds + r*S + c) = o;
  }
  {
    int chunk = 256 + t, r = chunk >> 2, c = (chunk & 3)*8;
    h8 o;
    #pragma unroll
    for (int j = 0; j < 4; ++j) {
      o[j]   = (_Float16)__expf((float)R.v1[j]   - R.k10[j]);
      o[4+j] = (_Float16)__expf((float)R.v1[4+j] - R.k11[j]);
    }
    *(h8*)(lds + r*S + c) = o;
  }
}

// ---------------- unified 128x128 double-buffered GEMM, XCD-chunked grid ----------------
// C[i][j] = sum_k A[i][k]*B[j][k]. 4 waves (2x2 of 64x64). BK=32, 2-phase pipeline.
// MA: 0 = f16 via global_load_lds, 1 = f32->f16 reg-staged, 3 = f16-L exp(v-kofs) reg-staged
// MB: 0 = f16 via global_load_lds, 1 = f32->f16 reg-staged
// EPI: 0 = f32 store; 1 = dual f16 store (C + C^T) + softmax partials; 2 = dual f16 store
// Epilogue C-image uses XOR-swizzled column groups: group' = (c>>3) ^ ((r>>3)&7).
// This makes the transposed gather (stride 8 rows = 544 dwords === 0 mod 32 banks)
// spread over 8 banks instead of 16-way single-bank conflicts.
// Grid: 1D, 16*TY tiles * 16 batches; 2 batches per XCD; by-fast tile order.
template<int MA, int MB, int EPI, int TY>
__global__ __launch_bounds__(256) void gemm128(
    const void* __restrict__ Ap, long sA,
    const void* __restrict__ Bp, long sB,
    void* __restrict__ Cp, long sC, int ldc,
    void* __restrict__ C2p, long sC2, int ldc2,
    int lda, int ldb, int K,
    const float* __restrict__ kofs,
    float* __restrict__ rowPM, float* __restrict__ rowPS,
    float* __restrict__ colPM, float* __restrict__ colPS)
{
  constexpr int SA = (MA == 0) ? 32 : 40;
  constexpr int SB = (MB == 0) ? 32 : 40;
  constexpr int ASZ = 128*SA, BSZ = 128*SB;
  constexpr int DB = 2*ASZ + 2*BSZ;
  constexpr int SMEM = (EPI >= 1 && DB < 128*136) ? 128*136 : DB;
  __shared__ _Float16 smem[SMEM];

  // XCD-chunked mapping: bid%8 = XCD; each XCD owns 2 consecutive batches
  constexpr int TILES = 16*TY;
  const int bid = blockIdx.x;
  const int xcd = bid & 7, slot = bid >> 3;
  const int b = xcd*2 + slot/TILES;
  const int tile = slot % TILES;
  const int by = tile % TY, bx = tile / TY;   // by-fast: B-panel reuse within XCD
  const int row0 = bx*128, col0 = by*128;

  const int t = threadIdx.x, w = t >> 6, l = t & 63;
  const int wr = w >> 1, wc = w & 1, l15 = l & 15, lg = l >> 4;

  const void* Ab;
  const void* Bb;
  if constexpr (MA == 1) Ab = (const void*)((const float*)Ap + (long)b*sA);
  else                   Ab = (const void*)((const _Float16*)Ap + (long)b*sA);
  if constexpr (MB == 1) Bb = (const void*)((const float*)Bp + (long)b*sB);
  else                   Bb = (const void*)((const _Float16*)Bp + (long)b*sB);

  const float* ko = nullptr;
  if constexpr (MA == 3) ko = kofs + (long)b*Nn;

  fx4 acc[4][4];
  #pragma unroll
  for (int fi = 0; fi < 4; ++fi)
    #pragma unroll
    for (int fj = 0; fj < 4; ++fj)
      acc[fi][fj] = (fx4){0.f, 0.f, 0.f, 0.f};

  const int NT = K/32;
  fx4 regA[4], regB[4];
  RegsA3 rA3;

  // prologue: tile 0 into buffer 0
  if constexpr (MA == 0)      stage_gld((const _Float16*)Ab, lda, row0, 0, smem, t);
  else if constexpr (MA == 1) load_f32((const float*)Ab, lda, row0, 0, t, regA);
  else                        load_A3((const _Float16*)Ab, lda, row0, 0, t, ko, rA3);
  if constexpr (MB == 0)      stage_gld((const _Float16*)Bb, ldb, col0, 0, smem + 2*ASZ, t);
  else                        load_f32((const float*)Bb, ldb, col0, 0, t, regB);
  if constexpr (MA == 1)      write_cvt<SA>(regA, smem, t);
  if constexpr (MA == 3)      write_A3<SA>(rA3, smem, t);
  if constexpr (MB == 1)      write_cvt<SB>(regB, smem + 2*ASZ, t);
  __syncthreads();

  for (int kt = 0; kt < NT; ++kt) {
    const int cur = kt & 1, nxt = cur ^ 1;
    const int k1 = (kt + 1)*32;
    _Float16* cA = smem + cur*ASZ;
    _Float16* cB = smem + 2*ASZ + cur*BSZ;
    _Float16* nA = smem + nxt*ASZ;
    _Float16* nB = smem + 2*ASZ + nxt*BSZ;

    if (kt + 1 < NT) {
      if constexpr (MA == 0)      stage_gld((const _Float16*)Ab, lda, row0, k1, nA, t);
      else if constexpr (MA == 1) load_f32((const float*)Ab, lda, row0, k1, t, regA);
      else                        load_A3((const _Float16*)Ab, lda, row0, k1, t, ko, rA3);
      if constexpr (MB == 0)      stage_gld((const _Float16*)Bb, ldb, col0, k1, nB, t);
      else                        load_f32((const float*)Bb, ldb, col0, k1, t, regB);
    }

    h8 af[4], bf[4];
    #pragma unroll
    for (int fi = 0; fi < 4; ++fi)
      af[fi] = *(const h8*)(cA + (wr*64 + fi*16 + l15)*SA + lg*8);
    #pragma unroll
    for (int fj = 0; fj < 4; ++fj)
      bf[fj] = *(const h8*)(cB + (wc*64 + fj*16 + l15)*SB + lg*8);
    #pragma unroll
    for (int fi = 0; fi < 4; ++fi)
      #pragma unroll
      for (int fj = 0; fj < 4; ++fj)
        acc[fi][fj] = __builtin_amdgcn_mfma_f32_16x16x32_f16(af[fi], bf[fj], acc[fi][fj], 0, 0, 0);

    if (kt + 1 < NT) {
      if constexpr (MA == 1) write_cvt<SA>(regA, nA, t);
      if constexpr (MA == 3) write_A3<SA>(rA3, nA, t);
      if constexpr (MB == 1) write_cvt<SB>(regB, nB, t);
    }
    __syncthreads();
  }

  if constexpr (EPI == 0) {
    float* Cb = (float*)Cp + (long)b*sC;
    #pragma unroll
    for (int fi = 0; fi < 4; ++fi)
      #pragma unroll
      for (int fj = 0; fj < 4; ++fj)
        #pragma unroll
        for (int j = 0; j < 4; ++j)
          Cb[(long)(row0 + wr*64 + fi*16 + lg*4 + j)*ldc + col0 + wc*64 + fj*16 + l15] = acc[fi][fj][j];
  }

  if constexpr (EPI >= 1) {
    if constexpr (EPI == 1) {
      // round acc to f16 precision (stored Lh/Lt and the softmax stats stay consistent)
      #pragma unroll
      for (int fi = 0; fi < 4; ++fi)
        #pragma unroll
        for (int fj = 0; fj < 4; ++fj)
          #pragma unroll
          for (int j = 0; j < 4; ++j)
            acc[fi][fj][j] = (float)(_Float16)acc[fi][fj][j];
    }

    // swizzled LDS image: (r,c) -> r*136 + (((c>>3) ^ ((r>>3)&7))<<3 | (c&7))
    #pragma unroll
    for (int fi = 0; fi < 4; ++fi) {
      #pragma unroll
      for (int j = 0; j < 4; ++j) {
        int rr = wr*64 + fi*16 + lg*4 + j;
        int key = (rr >> 3) & 7;
        #pragma unroll
        for (int fj = 0; fj < 4; ++fj) {
          int cc = wc*64 + fj*16 + l15;
          smem[rr*136 + ((((cc >> 3) ^ key) << 3) | (cc & 7))] = (_Float16)acc[fi][fj][j];
        }
      }
    }
    __syncthreads();
    _Float16* Cb  = (_Float16*)Cp  + (long)b*sC;
    _Float16* C2b = (_Float16*)C2p + (long)b*sC2;
    // row-major store: read swizzled group
    #pragma unroll
    for (int rd = 0; rd < 8; ++rd) {
      int r = rd*16 + (t >> 4);
      int g = (t & 15) ^ ((r >> 3) & 7);
      h8 v = *(const h8*)(smem + r*136 + g*8);
      *(h8*)(Cb + (long)(row0 + r)*ldc + col0 + (t & 15)*8) = v;
    }
    // transposed store: gather column dl over rows 8q..8q+7 (lane-static key = q&7)
    {
      const int q = t & 15, keyq = q & 7, n8 = q*8;
      #pragma unroll
      for (int rd = 0; rd < 8; ++rd) {
        int dl = rd*16 + (t >> 4);
        int gbase = ((dl >> 3) ^ keyq) << 3, c7 = dl & 7;
        h8 v;
        #pragma unroll
        for (int i = 0; i < 8; ++i)
          v[i] = smem[(n8 + i)*136 + gbase + c7];
        *(h8*)(C2b + (long)(col0 + dl)*ldc2 + row0 + n8) = v;
      }
    }
  }

  if constexpr (EPI == 1) {
    // row partials over this wave's 64-col half
    float rm[4][4], rs[4][4];
    #pragma unroll
    for (int fi = 0; fi < 4; ++fi)
      #pragma unroll
      for (int j = 0; j < 4; ++j)
        rm[fi][j] = fmaxf(fmaxf(acc[fi][0][j], acc[fi][1][j]),
                          fmaxf(acc[fi][2][j], acc[fi][3][j]));
    #pragma unroll
    for (int m = 1; m < 16; m <<= 1)
      #pragma unroll
      for (int fi = 0; fi < 4; ++fi)
        #pragma unroll
        for (int j = 0; j < 4; ++j)
          rm[fi][j] = fmaxf(rm[fi][j], __shfl_xor(rm[fi][j], m, 64));
    #pragma unroll
    for (int fi = 0; fi < 4; ++fi)
      #pragma unroll
      for (int j = 0; j < 4; ++j) {
        float s = 0.f;
        #pragma unroll
        for (int fj = 0; fj < 4; ++fj)
          s += __expf(acc[fi][fj][j] - rm[fi][j]);
        rs[fi][j] = s;
      }
    #pragma unroll
    for (int m = 1; m < 16; m <<= 1)
      #pragma unroll
      for (int fi = 0; fi < 4; ++fi)
        #pragma unroll
        for (int j = 0; j < 4; ++j)
          rs[fi][j] += __shfl_xor(rs[fi][j], m, 64);
    if (l15 == 0) {
      #pragma unroll
      for (int fi = 0; fi < 4; ++fi)
        #pragma unroll
        for (int j = 0; j < 4; ++j) {
          int row = row0 + wr*64 + fi*16 + lg*4 + j;
          long idx = ((long)b*Nn + row)*32 + by*2 + wc;
          rowPM[idx] = rm[fi][j];
          rowPS[idx] = rs[fi][j];
        }
    }
    // col partials over this wave's 64-row half
    float cm[4], cs[4];
    #pragma unroll
    for (int fj = 0; fj < 4; ++fj) {
      float v = -3.4e38f;
      #pragma unroll
      for (int fi = 0; fi < 4; ++fi)
        #pragma unroll
        for (int j = 0; j < 4; ++j)
          v = fmaxf(v, acc[fi][fj][j]);
      cm[fj] = v;
    }
    #pragma unroll
    for (int fj = 0; fj < 4; ++fj) {
      cm[fj] = fmaxf(cm[fj], __shfl_xor(cm[fj], 16, 64));
      cm[fj] = fmaxf(cm[fj], __shfl_xor(cm[fj], 32, 64));
    }
    #pragma unroll
    for (int fj = 0; fj < 4; ++fj) {
      float s = 0.f;
      #pragma unroll
      for (int fi = 0; fi < 4; ++fi)
        #pragma unroll
        for (int j = 0; j < 4; ++j)
          s += __expf(acc[fi][fj][j] - cm[fj]);
      cs[fj] = s;
    }
    #pragma unroll
    for (int fj = 0; fj < 4; ++fj) {
      cs[fj] += __shfl_xor(cs[fj], 16, 64);
      cs[fj] += __shfl_xor(cs[fj], 32, 64);
    }
    if (l < 16) {
      #pragma unroll
      for (int fj = 0; fj < 4; ++fj) {
        int col = col0 + wc*64 + fj*16 + l15;
        long idx = ((long)b*Nn + col)*32 + bx*2 + wr;
        colPM[idx] = cm[fj];
        colPS[idx] = cs[fj];
      }
    }
  }
}

// ---------------- x2 f32 -> x2h f16 + x2hT f16 ----------------
__global__ __launch_bounds__(256) void convert_x2(const float* __restrict__ x2,
    _Float16* __restrict__ x2h, _Float16* __restrict__ x2hT)
{
  __shared__ _Float16 lt[64*66];
  const int b = blockIdx.z, m0 = blockIdx.x*64, d0 = blockIdx.y*64;
  const int t = threadIdx.x;
  const float* xb = x2 + (long)b*Nn*Dn;
  _Float16* hb = x2h + (long)b*Nn*Dn;
  #pragma unroll
  for (int rd = 0; rd < 4; ++rd) {
    int r = rd*16 + (t >> 4), c = (t & 15)*4;
    fx4 v = *(const fx4*)(xb + (long)(m0 + r)*Dn + d0 + c);
    h4 h;
    #pragma unroll
    for (int i = 0; i < 4; ++i) { h[i] = (_Float16)v[i]; lt[r*66 + c + i] = h[i]; }
    *(h4*)(hb + (long)(m0 + r)*Dn + d0 + c) = h;
  }
  __syncthreads();
  _Float16* tb = x2hT + (long)b*Dn*Nn;
  #pragma unroll
  for (int rd = 0; rd < 4; ++rd) {
    int dl = rd*16 + (t >> 4), ml = (t & 15)*4;
    h4 h;
    #pragma unroll
    for (int i = 0; i < 4; ++i) h[i] = lt[(ml + i)*66 + dl];
    *(h4*)(tb + (long)(d0 + dl)*Nn + m0 + ml) = h;
  }
}

// ---------------- combine 32 partials per row/col -> ofs = max + log(sum) ----------------
__global__ __launch_bounds__(256) void reduce_stats(
    const float* __restrict__ rowPM, const float* __restrict__ rowPS,
    const float* __restrict__ colPM, const float* __restrict__ colPS,
    float* __restrict__ rofs, float* __restrict__ cofs)
{
  const int w = threadIdx.x >> 6, l = threadIdx.x & 63;
  const long row = (long)blockIdx.x*4 + w;
  const float* PM = blockIdx.y ? colPM : rowPM;
  const float* PS = blockIdx.y ? colPS : rowPS;
  float m0 = PM[row*32 + (l & 31)];
  float s0 = PS[row*32 + (l & 31)];
  float m = m0;
  #pragma unroll
  for (int k = 1; k < 32; k <<= 1) m = fmaxf(m, __shfl_xor(m, k, 64));
  float v = s0 * __expf(m0 - m);
  #pragma unroll
  for (int k = 1; k < 32; k <<= 1) v += __shfl_xor(v, k, 64);
  if (l == 0) {
    float ofs = m + __logf(v);
    if (blockIdx.y == 0) rofs[row] = ofs;
    else                 cofs[row] = ofs;
  }
}

// ---------------- finalize_AQ: A_D[n][m] = exp(Lh-rofs[n]); A_Q[m][n] = exp(Lh-cofs[m]) ----
__global__ __launch_bounds__(256) void finalize_AQ(const _Float16* __restrict__ Lh,
    float* __restrict__ AD, float* __restrict__ AQ,
    const float* __restrict__ rofs, const float* __restrict__ cofs)
{
  __shared__ float l2[64*65];
  const int b = blockIdx.z, n0 = blockIdx.x*64, m0 = blockIdx.y*64;
  const int t = threadIdx.x;
  const _Float16* Lb = Lh + (long)b*Nn*Nn;
  float* Db = AD + (long)b*Nn*Nn;
  #pragma unroll
  for (int rd = 0; rd < 4; ++rd) {
    int r = rd*16 + (t >> 4), c = (t & 15)*4;
    h4 v = *(const h4*)(Lb + (long)(n0 + r)*Nn + m0 + c);
    float ro = rofs[(long)b*Nn + n0 + r];
    fx4 co = *(const fx4*)(cofs + (long)b*Nn + m0 + c);
    fx4 e1;
    #pragma unroll
    for (int i = 0; i < 4; ++i) {
      float lv = (float)v[i];
      e1[i] = __expf(lv - ro);
      l2[r*65 + c + i] = __expf(lv - co[i]);
    }
    *(fx4*)(Db + (long)(n0 + r)*Nn + m0 + c) = e1;
  }
  __syncthreads();
  float* Qb = AQ + (long)b*Nn*Nn;
  #pragma unroll
  for (int rd = 0; rd < 4; ++rd) {
    int ml = rd*16 + (t >> 4), nl = (t & 15)*4;
    fx4 q;
    #pragma unroll
    for (int i = 0; i < 4; ++i) q[i] = l2[(nl + i)*65 + ml];
    *(fx4*)(Qb + (long)(m0 + ml)*Nn + n0 + nl) = q;
  }
}

} // namespace

extern "C" void kernel_launch(void* const* d_in, const int* in_sizes, int n_in,
                              void* d_out, int out_size, void* d_ws, size_t ws_size,
                              hipStream_t stream)
{
  const float* x1 = (const float*)d_in[0];
  const float* x2 = (const float*)d_in[1];
  // d_in[2] = node_mask: unused by reference
  const float* Wq = (const float*)d_in[3];

  float* out = (float*)d_out;
  float* C_Q = out;
  float* C_D = out + (long)Bn*Nn*Dn;
  float* A_D = out + 2L*Bn*Nn*Dn;
  float* A_Q = A_D + (long)Bn*Nn*Nn;

  // ws: Qh, QhT, x2h, x2hT (f16) + Lh (f16) + stats
  char* ws = (char*)d_ws;
  _Float16* Qh   = (_Float16*)ws;
  _Float16* QhT  = Qh   + (long)Bn*Nn*Dn;
  _Float16* x2h  = QhT  + (long)Bn*Dn*Nn;
  _Float16* x2hT = x2h  + (long)Bn*Nn*Dn;
  _Float16* Lh   = x2hT + (long)Bn*Dn*Nn;
  float* rofs = (float*)(Lh + (long)Bn*Nn*Nn);
  float* cofs = rofs + (long)Bn*Nn;

  // scratch aliased into the A_Q output region (serialized: Lt+partials -> ... -> A_Q at K5b)
  _Float16* Lt = (_Float16*)A_Q;                                      // 134 MB
  float* rowPM = (float*)((char*)A_Q + sizeof(_Float16)*(long)Bn*Nn*Nn);
  float* rowPS = rowPM + (long)Bn*Nn*32;
  float* colPM = rowPS + (long)Bn*Nn*32;
  float* colPS = colPM + (long)Bn*Nn*32;

  dim3 blk(256);

  // K0: x2 -> f16 + transposed
  convert_x2<<<dim3(32, 8, 16), blk, 0, stream>>>(x2, x2h, x2hT);

  // K1: Q = x1 @ Wq^T -> Qh + QhT (f16). B = Wq shared across batches (sB = 0).
  gemm128<1,1,2,4><<<dim3(1024), blk, 0, stream>>>(
      x1, (long)Nn*Dn, Wq, 0L,
      Qh, (long)Nn*Dn, Dn, QhT, (long)Dn*Nn, Nn,
      Dn, Dn, Dn,
      nullptr, nullptr, nullptr, nullptr, nullptr);

  // K2: Lh + Lt = (f16)(Qh @ x2h^T) dual-store + fused softmax partials
  gemm128<0,0,1,16><<<dim3(4096), blk, 0, stream>>>(
      Qh, (long)Nn*Dn, x2h, (long)Nn*Dn,
      Lh, (long)Nn*Nn, Nn, Lt, (long)Nn*Nn, Nn,
      Dn, Dn, Dn,
      nullptr, rowPM, rowPS, colPM, colPS);

  // K3: combine partials -> rofs/cofs = max + log(sum)
  reduce_stats<<<dim3(Bn*Nn/4, 2), blk, 0, stream>>>(rowPM, rowPS, colPM, colPS, rofs, cofs);

  // K4: C_Q = colsoftmax(L) @ x2  (exp fused in A staging from f16 Lh)
  gemm128<3,0,0,4><<<dim3(1024), blk, 0, stream>>>(
      Lh, (long)Nn*Nn, x2hT, (long)Dn*Nn,
      C_Q, (long)Nn*Dn, Dn, nullptr, 0L, 0,
      Nn, Nn, Nn,
      cofs, nullptr, nullptr, nullptr, nullptr);

  // K6: C_D = rowsoftmax(L)^T @ Q  (exp fused in A staging from f16 Lt, kofs = rofs)
  gemm128<3,0,0,4><<<dim3(1024), blk, 0, stream>>>(
      Lt, (long)Nn*Nn, QhT, (long)Dn*Nn,
      C_D, (long)Nn*Dn, Dn, nullptr, 0L, 0,
      Nn, Nn, Nn,
      rofs, nullptr, nullptr, nullptr, nullptr);

  // K5b: A_D + A_Q outputs (A_Q overwrites Lt/partials scratch — runs after K6)
  finalize_AQ<<<dim3(32, 32, 16), blk, 0, stream>>>(Lh, A_D, A_Q, rofs, cofs);
}

// Round 10
// 623.516 us; speedup vs baseline: 1.0900x; 1.0098x over previous
//
#include <hip/hip_runtime.h>

namespace {

constexpr int Bn = 16;
constexpr int Nn = 2048;
constexpr int Dn = 512;

typedef _Float16 h4 __attribute__((ext_vector_type(4)));
typedef _Float16 h8 __attribute__((ext_vector_type(8)));
typedef float    fx4 __attribute__((ext_vector_type(4)));

__device__ __forceinline__ void gld16(const _Float16* g, _Float16* l) {
  typedef const void __attribute__((address_space(1))) gvoid;
  typedef void __attribute__((address_space(3))) lvoid;
  __builtin_amdgcn_global_load_lds((gvoid*)g, (lvoid*)l, 16, 0, 0);
}

// issue 2 x global_load_lds (16B) for a 128x32 f16 tile (linear LDS [128][32])
__device__ __forceinline__ void stage_gld(const _Float16* __restrict__ g, int ld,
    int r0, int k0, _Float16* __restrict__ lds, int t)
{
  #pragma unroll
  for (int i = 0; i < 2; ++i) {
    int chunk = i*256 + t;
    gld16(g + (long)(r0 + (chunk >> 2))*ld + k0 + (chunk & 3)*8, lds + chunk*8);
  }
}

// issue 4 x global_load_lds (16B) for a 256x32 f16 tile (linear LDS [256][32])
__device__ __forceinline__ void stage_gld256(const _Float16* __restrict__ g, int ld,
    int r0, int k0, _Float16* __restrict__ lds, int t)
{
  #pragma unroll
  for (int i = 0; i < 4; ++i) {
    int chunk = i*256 + t;
    gld16(g + (long)(r0 + (chunk >> 2))*ld + k0 + (chunk & 3)*8, lds + chunk*8);
  }
}

// MODE 1 staging: f32 source -> regs
__device__ __forceinline__ void load_f32(const float* __restrict__ g, int ld,
    int r0, int k0, int t, fx4* regs)
{
  #pragma unroll
  for (int rd = 0; rd < 4; ++rd)
    regs[rd] = *(const fx4*)(g + (long)(r0 + rd*32 + (t >> 3))*ld + k0 + (t & 7)*4);
}
template<int S>
__device__ __forceinline__ void write_cvt(const fx4* regs, _Float16* __restrict__ lds, int t)
{
  const int c = (t & 7)*4;
  #pragma unroll
  for (int rd = 0; rd < 4; ++rd) {
    int r = rd*32 + (t >> 3);
    h4 o;
    #pragma unroll
    for (int i = 0; i < 4; ++i) o[i] = (_Float16)regs[rd][i];
    *(h4*)(lds + r*S + c) = o;
  }
}

// MODE 3 staging: f16 L source + exp(v - kofs[k]) -> f16
struct RegsA3 { h8 v0, v1; fx4 k00, k01, k10, k11; };
__device__ __forceinline__ void load_A3(const _Float16* __restrict__ g, int ld,
    int r0, int k0, int t, const float* __restrict__ kofs, RegsA3& R)
{
  {
    int chunk = t, r = chunk >> 2, c = (chunk & 3)*8;
    R.v0  = *(const h8*)(g + (long)(r0 + r)*ld + k0 + c);
    R.k00 = *(const fx4*)(kofs + k0 + c);
    R.k01 = *(const fx4*)(kofs + k0 + c + 4);
  }
  {
    int chunk = 256 + t, r = chunk >> 2, c = (chunk & 3)*8;
    R.v1  = *(const h8*)(g + (long)(r0 + r)*ld + k0 + c);
    R.k10 = *(const fx4*)(kofs + k0 + c);
    R.k11 = *(const fx4*)(kofs + k0 + c + 4);
  }
}
template<int S>
__device__ __forceinline__ void write_A3(const RegsA3& R, _Float16* __restrict__ lds, int t)
{
  {
    int chunk = t, r = chunk >> 2, c = (chunk & 3)*8;
    h8 o;
    #pragma unroll
    for (int j = 0; j < 4; ++j) {
      o[j]   = (_Float16)__expf((float)R.v0[j]   - R.k00[j]);
      o[4+j] = (_Float16)__expf((float)R.v0[4+j] - R.k01[j]);
    }
    *(h8*)(lds + r*S + c) = o;
  }
  {
    int chunk = 256 + t, r = chunk >> 2, c = (chunk & 3)*8;
    h8 o;
    #pragma unroll
    for (int j = 0; j < 4; ++j) {
      o[j]   = (_Float16)__expf((float)R.v1[j]   - R.k10[j]);
      o[4+j] = (_Float16)__expf((float)R.v1[4+j] - R.k11[j]);
    }
    *(h8*)(lds + r*S + c) = o;
  }
}

// ---------------- unified 128x128 double-buffered GEMM, XCD-chunked grid ----------------
// (used for K1 q-proj and K2 logits; see gemm_expw for the wide K4/K6 shape)
// C[i][j] = sum_k A[i][k]*B[j][k]. 4 waves (2x2 of 64x64). BK=32, 2-phase pipeline.
// MA: 0 = f16 via global_load_lds, 1 = f32->f16 reg-staged, 3 = f16-L exp(v-kofs) reg-staged
// MB: 0 = f16 via global_load_lds, 1 = f32->f16 reg-staged
// EPI: 0 = f32 store; 1 = dual f16 store (C + C^T) + softmax partials; 2 = dual f16 store
// Epilogue C-image uses XOR-swizzled column groups: group' = (c>>3) ^ ((r>>3)&7).
template<int MA, int MB, int EPI, int TY>
__global__ __launch_bounds__(256) void gemm128(
    const void* __restrict__ Ap, long sA,
    const void* __restrict__ Bp, long sB,
    void* __restrict__ Cp, long sC, int ldc,
    void* __restrict__ C2p, long sC2, int ldc2,
    int lda, int ldb, int K,
    const float* __restrict__ kofs,
    float* __restrict__ rowPM, float* __restrict__ rowPS,
    float* __restrict__ colPM, float* __restrict__ colPS)
{
  constexpr int SA = (MA == 0) ? 32 : 40;
  constexpr int SB = (MB == 0) ? 32 : 40;
  constexpr int ASZ = 128*SA, BSZ = 128*SB;
  constexpr int DB = 2*ASZ + 2*BSZ;
  constexpr int SMEM = (EPI >= 1 && DB < 128*136) ? 128*136 : DB;
  __shared__ _Float16 smem[SMEM];

  // XCD-chunked mapping: bid%8 = XCD; each XCD owns 2 consecutive batches
  constexpr int TILES = 16*TY;
  const int bid = blockIdx.x;
  const int xcd = bid & 7, slot = bid >> 3;
  const int b = xcd*2 + slot/TILES;
  const int tile = slot % TILES;
  const int by = tile % TY, bx = tile / TY;   // by-fast: B-panel reuse within XCD
  const int row0 = bx*128, col0 = by*128;

  const int t = threadIdx.x, w = t >> 6, l = t & 63;
  const int wr = w >> 1, wc = w & 1, l15 = l & 15, lg = l >> 4;

  const void* Ab;
  const void* Bb;
  if constexpr (MA == 1) Ab = (const void*)((const float*)Ap + (long)b*sA);
  else                   Ab = (const void*)((const _Float16*)Ap + (long)b*sA);
  if constexpr (MB == 1) Bb = (const void*)((const float*)Bp + (long)b*sB);
  else                   Bb = (const void*)((const _Float16*)Bp + (long)b*sB);

  const float* ko = nullptr;
  if constexpr (MA == 3) ko = kofs + (long)b*Nn;

  fx4 acc[4][4];
  #pragma unroll
  for (int fi = 0; fi < 4; ++fi)
    #pragma unroll
    for (int fj = 0; fj < 4; ++fj)
      acc[fi][fj] = (fx4){0.f, 0.f, 0.f, 0.f};

  const int NT = K/32;
  fx4 regA[4], regB[4];
  RegsA3 rA3;

  // prologue: tile 0 into buffer 0
  if constexpr (MA == 0)      stage_gld((const _Float16*)Ab, lda, row0, 0, smem, t);
  else if constexpr (MA == 1) load_f32((const float*)Ab, lda, row0, 0, t, regA);
  else                        load_A3((const _Float16*)Ab, lda, row0, 0, t, ko, rA3);
  if constexpr (MB == 0)      stage_gld((const _Float16*)Bb, ldb, col0, 0, smem + 2*ASZ, t);
  else                        load_f32((const float*)Bb, ldb, col0, 0, t, regB);
  if constexpr (MA == 1)      write_cvt<SA>(regA, smem, t);
  if constexpr (MA == 3)      write_A3<SA>(rA3, smem, t);
  if constexpr (MB == 1)      write_cvt<SB>(regB, smem + 2*ASZ, t);
  __syncthreads();

  for (int kt = 0; kt < NT; ++kt) {
    const int cur = kt & 1, nxt = cur ^ 1;
    const int k1 = (kt + 1)*32;
    _Float16* cA = smem + cur*ASZ;
    _Float16* cB = smem + 2*ASZ + cur*BSZ;
    _Float16* nA = smem + nxt*ASZ;
    _Float16* nB = smem + 2*ASZ + nxt*BSZ;

    if (kt + 1 < NT) {
      if constexpr (MA == 0)      stage_gld((const _Float16*)Ab, lda, row0, k1, nA, t);
      else if constexpr (MA == 1) load_f32((const float*)Ab, lda, row0, k1, t, regA);
      else                        load_A3((const _Float16*)Ab, lda, row0, k1, t, ko, rA3);
      if constexpr (MB == 0)      stage_gld((const _Float16*)Bb, ldb, col0, k1, nB, t);
      else                        load_f32((const float*)Bb, ldb, col0, k1, t, regB);
    }

    h8 af[4], bf[4];
    #pragma unroll
    for (int fi = 0; fi < 4; ++fi)
      af[fi] = *(const h8*)(cA + (wr*64 + fi*16 + l15)*SA + lg*8);
    #pragma unroll
    for (int fj = 0; fj < 4; ++fj)
      bf[fj] = *(const h8*)(cB + (wc*64 + fj*16 + l15)*SB + lg*8);
    #pragma unroll
    for (int fi = 0; fi < 4; ++fi)
      #pragma unroll
      for (int fj = 0; fj < 4; ++fj)
        acc[fi][fj] = __builtin_amdgcn_mfma_f32_16x16x32_f16(af[fi], bf[fj], acc[fi][fj], 0, 0, 0);

    if (kt + 1 < NT) {
      if constexpr (MA == 1) write_cvt<SA>(regA, nA, t);
      if constexpr (MA == 3) write_A3<SA>(rA3, nA, t);
      if constexpr (MB == 1) write_cvt<SB>(regB, nB, t);
    }
    __syncthreads();
  }

  if constexpr (EPI == 0) {
    float* Cb = (float*)Cp + (long)b*sC;
    #pragma unroll
    for (int fi = 0; fi < 4; ++fi)
      #pragma unroll
      for (int fj = 0; fj < 4; ++fj)
        #pragma unroll
        for (int j = 0; j < 4; ++j)
          Cb[(long)(row0 + wr*64 + fi*16 + lg*4 + j)*ldc + col0 + wc*64 + fj*16 + l15] = acc[fi][fj][j];
  }

  if constexpr (EPI >= 1) {
    if constexpr (EPI == 1) {
      // round acc to f16 precision (stored Lh/Lt and the softmax stats stay consistent)
      #pragma unroll
      for (int fi = 0; fi < 4; ++fi)
        #pragma unroll
        for (int fj = 0; fj < 4; ++fj)
          #pragma unroll
          for (int j = 0; j < 4; ++j)
            acc[fi][fj][j] = (float)(_Float16)acc[fi][fj][j];
    }

    // swizzled LDS image: (r,c) -> r*136 + (((c>>3) ^ ((r>>3)&7))<<3 | (c&7))
    #pragma unroll
    for (int fi = 0; fi < 4; ++fi) {
      #pragma unroll
      for (int j = 0; j < 4; ++j) {
        int rr = wr*64 + fi*16 + lg*4 + j;
        int key = (rr >> 3) & 7;
        #pragma unroll
        for (int fj = 0; fj < 4; ++fj) {
          int cc = wc*64 + fj*16 + l15;
          smem[rr*136 + ((((cc >> 3) ^ key) << 3) | (cc & 7))] = (_Float16)acc[fi][fj][j];
        }
      }
    }
    __syncthreads();
    _Float16* Cb  = (_Float16*)Cp  + (long)b*sC;
    _Float16* C2b = (_Float16*)C2p + (long)b*sC2;
    // row-major store: read swizzled group
    #pragma unroll
    for (int rd = 0; rd < 8; ++rd) {
      int r = rd*16 + (t >> 4);
      int g = (t & 15) ^ ((r >> 3) & 7);
      h8 v = *(const h8*)(smem + r*136 + g*8);
      *(h8*)(Cb + (long)(row0 + r)*ldc + col0 + (t & 15)*8) = v;
    }
    // transposed store: gather column dl over rows 8q..8q+7 (lane-static key = q&7)
    {
      const int q = t & 15, keyq = q & 7, n8 = q*8;
      #pragma unroll
      for (int rd = 0; rd < 8; ++rd) {
        int dl = rd*16 + (t >> 4);
        int gbase = ((dl >> 3) ^ keyq) << 3, c7 = dl & 7;
        h8 v;
        #pragma unroll
        for (int i = 0; i < 8; ++i)
          v[i] = smem[(n8 + i)*136 + gbase + c7];
        *(h8*)(C2b + (long)(col0 + dl)*ldc2 + row0 + n8) = v;
      }
    }
  }

  if constexpr (EPI == 1) {
    // row partials over this wave's 64-col half
    float rm[4][4], rs[4][4];
    #pragma unroll
    for (int fi = 0; fi < 4; ++fi)
      #pragma unroll
      for (int j = 0; j < 4; ++j)
        rm[fi][j] = fmaxf(fmaxf(acc[fi][0][j], acc[fi][1][j]),
                          fmaxf(acc[fi][2][j], acc[fi][3][j]));
    #pragma unroll
    for (int m = 1; m < 16; m <<= 1)
      #pragma unroll
      for (int fi = 0; fi < 4; ++fi)
        #pragma unroll
        for (int j = 0; j < 4; ++j)
          rm[fi][j] = fmaxf(rm[fi][j], __shfl_xor(rm[fi][j], m, 64));
    #pragma unroll
    for (int fi = 0; fi < 4; ++fi)
      #pragma unroll
      for (int j = 0; j < 4; ++j) {
        float s = 0.f;
        #pragma unroll
        for (int fj = 0; fj < 4; ++fj)
          s += __expf(acc[fi][fj][j] - rm[fi][j]);
        rs[fi][j] = s;
      }
    #pragma unroll
    for (int m = 1; m < 16; m <<= 1)
      #pragma unroll
      for (int fi = 0; fi < 4; ++fi)
        #pragma unroll
        for (int j = 0; j < 4; ++j)
          rs[fi][j] += __shfl_xor(rs[fi][j], m, 64);
    if (l15 == 0) {
      #pragma unroll
      for (int fi = 0; fi < 4; ++fi)
        #pragma unroll
        for (int j = 0; j < 4; ++j) {
          int row = row0 + wr*64 + fi*16 + lg*4 + j;
          long idx = ((long)b*Nn + row)*32 + by*2 + wc;
          rowPM[idx] = rm[fi][j];
          rowPS[idx] = rs[fi][j];
        }
    }
    // col partials over this wave's 64-row half
    float cm[4], cs[4];
    #pragma unroll
    for (int fj = 0; fj < 4; ++fj) {
      float v = -3.4e38f;
      #pragma unroll
      for (int fi = 0; fi < 4; ++fi)
        #pragma unroll
        for (int j = 0; j < 4; ++j)
          v = fmaxf(v, acc[fi][fj][j]);
      cm[fj] = v;
    }
    #pragma unroll
    for (int fj = 0; fj < 4; ++fj) {
      cm[fj] = fmaxf(cm[fj], __shfl_xor(cm[fj], 16, 64));
      cm[fj] = fmaxf(cm[fj], __shfl_xor(cm[fj], 32, 64));
    }
    #pragma unroll
    for (int fj = 0; fj < 4; ++fj) {
      float s = 0.f;
      #pragma unroll
      for (int fi = 0; fi < 4; ++fi)
        #pragma unroll
        for (int j = 0; j < 4; ++j)
          s += __expf(acc[fi][fj][j] - cm[fj]);
      cs[fj] = s;
    }
    #pragma unroll
    for (int fj = 0; fj < 4; ++fj) {
      cs[fj] += __shfl_xor(cs[fj], 16, 64);
      cs[fj] += __shfl_xor(cs[fj], 32, 64);
    }
    if (l < 16) {
      #pragma unroll
      for (int fj = 0; fj < 4; ++fj) {
        int col = col0 + wc*64 + fj*16 + l15;
        long idx = ((long)b*Nn + col)*32 + bx*2 + wr;
        colPM[idx] = cm[fj];
        colPS[idx] = cs[fj];
      }
    }
  }
}

// ---------------- K4/K6: exp-weight GEMM, 128x256 tile, 4 waves of 64x128 ----------------
// C[i][j] = sum_k exp(A[i][k]-kofs[k]) * B[j][k].  A: f16 [2048][2048], B: f16 [512][2048].
// 32 MFMA per wave per k-step vs ~80cy exp staging -> 2:1 MFMA:VALU (was 1:1).
// A exp'd once per 256-col tile (2x redundancy instead of 4x). B via global_load_lds.
// LDS 52 KB; __launch_bounds__(256,2) -> VGPR<=256 -> 2 blocks/CU.
__global__ __launch_bounds__(256, 2) void gemm_expw(
    const _Float16* __restrict__ Ap, const _Float16* __restrict__ Bp,
    float* __restrict__ Cp, const float* __restrict__ kofs)
{
  constexpr int SA = 40;
  constexpr int ASZ = 128*SA;       // f16 elems
  constexpr int BSZ = 256*32;
  __shared__ _Float16 smem[2*ASZ + 2*BSZ];   // 52 KB

  // XCD-chunked: 512 blocks; xcd = bid&7 owns 2 batches; 32 tiles/batch, by-fast
  const int bid = blockIdx.x;
  const int xcd = bid & 7, slot = bid >> 3;
  const int b = xcd*2 + (slot >> 5);
  const int tile = slot & 31;
  const int by = tile & 1, bx = tile >> 1;
  const int row0 = bx*128, col0 = by*256;

  const int t = threadIdx.x, w = t >> 6, l = t & 63;
  const int wr = w >> 1, wc = w & 1, l15 = l & 15, lg = l >> 4;

  const _Float16* Ab = Ap + (long)b*Nn*Nn;
  const _Float16* Bb = Bp + (long)b*Dn*Nn;
  const float* ko = kofs + (long)b*Nn;

  fx4 acc[4][8];
  #pragma unroll
  for (int fi = 0; fi < 4; ++fi)
    #pragma unroll
    for (int fj = 0; fj < 8; ++fj)
      acc[fi][fj] = (fx4){0.f, 0.f, 0.f, 0.f};

  const int NT = Nn/32;
  RegsA3 rA3;

  // prologue
  load_A3(Ab, Nn, row0, 0, t, ko, rA3);
  stage_gld256(Bb, Nn, col0, 0, smem + 2*ASZ, t);
  write_A3<SA>(rA3, smem, t);
  __syncthreads();

  for (int kt = 0; kt < NT; ++kt) {
    const int cur = kt & 1, nxt = cur ^ 1;
    const int k1 = (kt + 1)*32;
    _Float16* cA = smem + cur*ASZ;
    _Float16* cB = smem + 2*ASZ + cur*BSZ;
    _Float16* nA = smem + nxt*ASZ;
    _Float16* nB = smem + 2*ASZ + nxt*BSZ;

    if (kt + 1 < NT) {
      load_A3(Ab, Nn, row0, k1, t, ko, rA3);
      stage_gld256(Bb, Nn, col0, k1, nB, t);
    }

    h8 af[4], bf[8];
    #pragma unroll
    for (int fi = 0; fi < 4; ++fi)
      af[fi] = *(const h8*)(cA + (wr*64 + fi*16 + l15)*SA + lg*8);
    #pragma unroll
    for (int fj = 0; fj < 8; ++fj)
      bf[fj] = *(const h8*)(cB + (wc*128 + fj*16 + l15)*32 + lg*8);
    #pragma unroll
    for (int fi = 0; fi < 4; ++fi)
      #pragma unroll
      for (int fj = 0; fj < 8; ++fj)
        acc[fi][fj] = __builtin_amdgcn_mfma_f32_16x16x32_f16(af[fi], bf[fj], acc[fi][fj], 0, 0, 0);

    if (kt + 1 < NT)
      write_A3<SA>(rA3, nA, t);
    __syncthreads();
  }

  float* Cb = Cp + (long)b*Nn*Dn;
  #pragma unroll
  for (int fi = 0; fi < 4; ++fi)
    #pragma unroll
    for (int fj = 0; fj < 8; ++fj)
      #pragma unroll
      for (int j = 0; j < 4; ++j)
        Cb[(long)(row0 + wr*64 + fi*16 + lg*4 + j)*Dn + col0 + wc*128 + fj*16 + l15] = acc[fi][fj][j];
}

// ---------------- x2 f32 -> x2h f16 + x2hT f16 ----------------
__global__ __launch_bounds__(256) void convert_x2(const float* __restrict__ x2,
    _Float16* __restrict__ x2h, _Float16* __restrict__ x2hT)
{
  __shared__ _Float16 lt[64*66];
  const int b = blockIdx.z, m0 = blockIdx.x*64, d0 = blockIdx.y*64;
  const int t = threadIdx.x;
  const float* xb = x2 + (long)b*Nn*Dn;
  _Float16* hb = x2h + (long)b*Nn*Dn;
  #pragma unroll
  for (int rd = 0; rd < 4; ++rd) {
    int r = rd*16 + (t >> 4), c = (t & 15)*4;
    fx4 v = *(const fx4*)(xb + (long)(m0 + r)*Dn + d0 + c);
    h4 h;
    #pragma unroll
    for (int i = 0; i < 4; ++i) { h[i] = (_Float16)v[i]; lt[r*66 + c + i] = h[i]; }
    *(h4*)(hb + (long)(m0 + r)*Dn + d0 + c) = h;
  }
  __syncthreads();
  _Float16* tb = x2hT + (long)b*Dn*Nn;
  #pragma unroll
  for (int rd = 0; rd < 4; ++rd) {
    int dl = rd*16 + (t >> 4), ml = (t & 15)*4;
    h4 h;
    #pragma unroll
    for (int i = 0; i < 4; ++i) h[i] = lt[(ml + i)*66 + dl];
    *(h4*)(tb + (long)(d0 + dl)*Nn + m0 + ml) = h;
  }
}

// ---------------- combine 32 partials per row/col -> ofs = max + log(sum) ----------------
__global__ __launch_bounds__(256) void reduce_stats(
    const float* __restrict__ rowPM, const float* __restrict__ rowPS,
    const float* __restrict__ colPM, const float* __restrict__ colPS,
    float* __restrict__ rofs, float* __restrict__ cofs)
{
  const int w = threadIdx.x >> 6, l = threadIdx.x & 63;
  const long row = (long)blockIdx.x*4 + w;
  const float* PM = blockIdx.y ? colPM : rowPM;
  const float* PS = blockIdx.y ? colPS : rowPS;
  float m0 = PM[row*32 + (l & 31)];
  float s0 = PS[row*32 + (l & 31)];
  float m = m0;
  #pragma unroll
  for (int k = 1; k < 32; k <<= 1) m = fmaxf(m, __shfl_xor(m, k, 64));
  float v = s0 * __expf(m0 - m);
  #pragma unroll
  for (int k = 1; k < 32; k <<= 1) v += __shfl_xor(v, k, 64);
  if (l == 0) {
    float ofs = m + __logf(v);
    if (blockIdx.y == 0) rofs[row] = ofs;
    else                 cofs[row] = ofs;
  }
}

// ---------------- finalize_AQ: A_D[n][m] = exp(Lh-rofs[n]); A_Q[m][n] = exp(Lh-cofs[m]) ----
__global__ __launch_bounds__(256) void finalize_AQ(const _Float16* __restrict__ Lh,
    float* __restrict__ AD, float* __restrict__ AQ,
    const float* __restrict__ rofs, const float* __restrict__ cofs)
{
  __shared__ float l2[64*65];
  const int b = blockIdx.z, n0 = blockIdx.x*64, m0 = blockIdx.y*64;
  const int t = threadIdx.x;
  const _Float16* Lb = Lh + (long)b*Nn*Nn;
  float* Db = AD + (long)b*Nn*Nn;
  #pragma unroll
  for (int rd = 0; rd < 4; ++rd) {
    int r = rd*16 + (t >> 4), c = (t & 15)*4;
    h4 v = *(const h4*)(Lb + (long)(n0 + r)*Nn + m0 + c);
    float ro = rofs[(long)b*Nn + n0 + r];
    fx4 co = *(const fx4*)(cofs + (long)b*Nn + m0 + c);
    fx4 e1;
    #pragma unroll
    for (int i = 0; i < 4; ++i) {
      float lv = (float)v[i];
      e1[i] = __expf(lv - ro);
      l2[r*65 + c + i] = __expf(lv - co[i]);
    }
    *(fx4*)(Db + (long)(n0 + r)*Nn + m0 + c) = e1;
  }
  __syncthreads();
  float* Qb = AQ + (long)b*Nn*Nn;
  #pragma unroll
  for (int rd = 0; rd < 4; ++rd) {
    int ml = rd*16 + (t >> 4), nl = (t & 15)*4;
    fx4 q;
    #pragma unroll
    for (int i = 0; i < 4; ++i) q[i] = l2[(nl + i)*65 + ml];
    *(fx4*)(Qb + (long)(m0 + ml)*Nn + n0 + nl) = q;
  }
}

} // namespace

extern "C" void kernel_launch(void* const* d_in, const int* in_sizes, int n_in,
                              void* d_out, int out_size, void* d_ws, size_t ws_size,
                              hipStream_t stream)
{
  const float* x1 = (const float*)d_in[0];
  const float* x2 = (const float*)d_in[1];
  // d_in[2] = node_mask: unused by reference
  const float* Wq = (const float*)d_in[3];

  float* out = (float*)d_out;
  float* C_Q = out;
  float* C_D = out + (long)Bn*Nn*Dn;
  float* A_D = out + 2L*Bn*Nn*Dn;
  float* A_Q = A_D + (long)Bn*Nn*Nn;

  // ws: Qh, QhT, x2h, x2hT (f16) + Lh (f16) + stats
  char* ws = (char*)d_ws;
  _Float16* Qh   = (_Float16*)ws;
  _Float16* QhT  = Qh   + (long)Bn*Nn*Dn;
  _Float16* x2h  = QhT  + (long)Bn*Dn*Nn;
  _Float16* x2hT = x2h  + (long)Bn*Nn*Dn;
  _Float16* Lh   = x2hT + (long)Bn*Dn*Nn;
  float* rofs = (float*)(Lh + (long)Bn*Nn*Nn);
  float* cofs = rofs + (long)Bn*Nn;

  // scratch aliased into the A_Q output region (serialized: Lt+partials -> ... -> A_Q at K5b)
  _Float16* Lt = (_Float16*)A_Q;                                      // 134 MB
  float* rowPM = (float*)((char*)A_Q + sizeof(_Float16)*(long)Bn*Nn*Nn);
  float* rowPS = rowPM + (long)Bn*Nn*32;
  float* colPM = rowPS + (long)Bn*Nn*32;
  float* colPS = colPM + (long)Bn*Nn*32;

  dim3 blk(256);

  // K0: x2 -> f16 + transposed
  convert_x2<<<dim3(32, 8, 16), blk, 0, stream>>>(x2, x2h, x2hT);

  // K1: Q = x1 @ Wq^T -> Qh + QhT (f16). B = Wq shared across batches (sB = 0).
  gemm128<1,1,2,4><<<dim3(1024), blk, 0, stream>>>(
      x1, (long)Nn*Dn, Wq, 0L,
      Qh, (long)Nn*Dn, Dn, QhT, (long)Dn*Nn, Nn,
      Dn, Dn, Dn,
      nullptr, nullptr, nullptr, nullptr, nullptr);

  // K2: Lh + Lt = (f16)(Qh @ x2h^T) dual-store + fused softmax partials
  gemm128<0,0,1,16><<<dim3(4096), blk, 0, stream>>>(
      Qh, (long)Nn*Dn, x2h, (long)Nn*Dn,
      Lh, (long)Nn*Nn, Nn, Lt, (long)Nn*Nn, Nn,
      Dn, Dn, Dn,
      nullptr, rowPM, rowPS, colPM, colPS);

  // K3: combine partials -> rofs/cofs = max + log(sum)
  reduce_stats<<<dim3(Bn*Nn/4, 2), blk, 0, stream>>>(rowPM, rowPS, colPM, colPS, rofs, cofs);

  // K4: C_Q = colsoftmax(L) @ x2  (exp fused in A staging from f16 Lh; 128x256 tiles)
  gemm_expw<<<dim3(512), blk, 0, stream>>>(Lh, x2hT, C_Q, cofs);

  // K6: C_D = rowsoftmax(L)^T @ Q  (exp fused in A staging from f16 Lt; 128x256 tiles)
  gemm_expw<<<dim3(512), blk, 0, stream>>>(Lt, QhT, C_D, rofs);

  // K5b: A_D + A_Q outputs (A_Q overwrites Lt/partials scratch — runs after K6)
  finalize_AQ<<<dim3(32, 32, 16), blk, 0, stream>>>(Lh, A_D, A_Q, rofs, cofs);
}

// Round 11
// 605.843 us; speedup vs baseline: 1.1218x; 1.0292x over previous
//
#include <hip/hip_runtime.h>

namespace {

constexpr int Bn = 16;
constexpr int Nn = 2048;
constexpr int Dn = 512;

typedef _Float16 h4 __attribute__((ext_vector_type(4)));
typedef _Float16 h8 __attribute__((ext_vector_type(8)));
typedef float    fx4 __attribute__((ext_vector_type(4)));

__device__ __forceinline__ void gld16(const _Float16* g, _Float16* l) {
  typedef const void __attribute__((address_space(1))) gvoid;
  typedef void __attribute__((address_space(3))) lvoid;
  __builtin_amdgcn_global_load_lds((gvoid*)g, (lvoid*)l, 16, 0, 0);
}

// issue 2 x global_load_lds (16B) for a 128x32 f16 tile (linear LDS [128][32])
__device__ __forceinline__ void stage_gld(const _Float16* __restrict__ g, int ld,
    int r0, int k0, _Float16* __restrict__ lds, int t)
{
  #pragma unroll
  for (int i = 0; i < 2; ++i) {
    int chunk = i*256 + t;
    gld16(g + (long)(r0 + (chunk >> 2))*ld + k0 + (chunk & 3)*8, lds + chunk*8);
  }
}

// issue 4 x global_load_lds (16B) for a 256x32 f16 tile (linear LDS [256][32])
__device__ __forceinline__ void stage_gld256(const _Float16* __restrict__ g, int ld,
    int r0, int k0, _Float16* __restrict__ lds, int t)
{
  #pragma unroll
  for (int i = 0; i < 4; ++i) {
    int chunk = i*256 + t;
    gld16(g + (long)(r0 + (chunk >> 2))*ld + k0 + (chunk & 3)*8, lds + chunk*8);
  }
}

// MODE 1 staging: f32 source -> regs
__device__ __forceinline__ void load_f32(const float* __restrict__ g, int ld,
    int r0, int k0, int t, fx4* regs)
{
  #pragma unroll
  for (int rd = 0; rd < 4; ++rd)
    regs[rd] = *(const fx4*)(g + (long)(r0 + rd*32 + (t >> 3))*ld + k0 + (t & 7)*4);
}
template<int S>
__device__ __forceinline__ void write_cvt(const fx4* regs, _Float16* __restrict__ lds, int t)
{
  const int c = (t & 7)*4;
  #pragma unroll
  for (int rd = 0; rd < 4; ++rd) {
    int r = rd*32 + (t >> 3);
    h4 o;
    #pragma unroll
    for (int i = 0; i < 4; ++i) o[i] = (_Float16)regs[rd][i];
    *(h4*)(lds + r*S + c) = o;
  }
}

// MODE 3 staging: f16 L source + exp(v - kofs[k]) -> f16
struct RegsA3 { h8 v0, v1; fx4 k00, k01, k10, k11; };
__device__ __forceinline__ void load_A3(const _Float16* __restrict__ g, int ld,
    int r0, int k0, int t, const float* __restrict__ kofs, RegsA3& R)
{
  {
    int chunk = t, r = chunk >> 2, c = (chunk & 3)*8;
    R.v0  = *(const h8*)(g + (long)(r0 + r)*ld + k0 + c);
    R.k00 = *(const fx4*)(kofs + k0 + c);
    R.k01 = *(const fx4*)(kofs + k0 + c + 4);
  }
  {
    int chunk = 256 + t, r = chunk >> 2, c = (chunk & 3)*8;
    R.v1  = *(const h8*)(g + (long)(r0 + r)*ld + k0 + c);
    R.k10 = *(const fx4*)(kofs + k0 + c);
    R.k11 = *(const fx4*)(kofs + k0 + c + 4);
  }
}
template<int S>
__device__ __forceinline__ void write_A3(const RegsA3& R, _Float16* __restrict__ lds, int t)
{
  {
    int chunk = t, r = chunk >> 2, c = (chunk & 3)*8;
    h8 o;
    #pragma unroll
    for (int j = 0; j < 4; ++j) {
      o[j]   = (_Float16)__expf((float)R.v0[j]   - R.k00[j]);
      o[4+j] = (_Float16)__expf((float)R.v0[4+j] - R.k01[j]);
    }
    *(h8*)(lds + r*S + c) = o;
  }
  {
    int chunk = 256 + t, r = chunk >> 2, c = (chunk & 3)*8;
    h8 o;
    #pragma unroll
    for (int j = 0; j < 4; ++j) {
      o[j]   = (_Float16)__expf((float)R.v1[j]   - R.k10[j]);
      o[4+j] = (_Float16)__expf((float)R.v1[4+j] - R.k11[j]);
    }
    *(h8*)(lds + r*S + c) = o;
  }
}

// fused f32 softmax-output write from staged A regs: O[r][k] = exp(v - oofs[row])
// thread t covers rows r0+(t>>2) and r0+64+(t>>2), cols k0+(t&3)*8 .. +8 (coalesced)
__device__ __forceinline__ void write_Of32(const RegsA3& R, float* __restrict__ base,
    int ld, int r0, int k0, int t, float ro0, float ro1)
{
  const int r = t >> 2, c = (t & 3)*8;
  float* d0 = base + (long)(r0 + r)*ld + k0 + c;
  float* d1 = base + (long)(r0 + 64 + r)*ld + k0 + c;
  fx4 a0, a1;
  #pragma unroll
  for (int j = 0; j < 4; ++j) { a0[j] = __expf((float)R.v0[j] - ro0); a1[j] = __expf((float)R.v0[4+j] - ro0); }
  *(fx4*)d0 = a0; *(fx4*)(d0 + 4) = a1;
  #pragma unroll
  for (int j = 0; j < 4; ++j) { a0[j] = __expf((float)R.v1[j] - ro1); a1[j] = __expf((float)R.v1[4+j] - ro1); }
  *(fx4*)d1 = a0; *(fx4*)(d1 + 4) = a1;
}

// ---------------- unified 128x128 double-buffered GEMM, XCD-chunked grid ----------------
// (used for K1 q-proj and K2 logits; see gemm_expw for the wide K4/K6 shape)
// C[i][j] = sum_k A[i][k]*B[j][k]. 4 waves (2x2 of 64x64). BK=32, 2-phase pipeline.
// MA: 0 = f16 via global_load_lds, 1 = f32->f16 reg-staged
// MB: 0 = f16 via global_load_lds, 1 = f32->f16 reg-staged
// EPI: 1 = dual f16 store (C + C^T) + softmax partials; 2 = dual f16 store
// Epilogue C-image uses XOR-swizzled column groups: group' = (c>>3) ^ ((r>>3)&7).
template<int MA, int MB, int EPI, int TY>
__global__ __launch_bounds__(256) void gemm128(
    const void* __restrict__ Ap, long sA,
    const void* __restrict__ Bp, long sB,
    void* __restrict__ Cp, long sC, int ldc,
    void* __restrict__ C2p, long sC2, int ldc2,
    int lda, int ldb, int K,
    float* __restrict__ rowPM, float* __restrict__ rowPS,
    float* __restrict__ colPM, float* __restrict__ colPS)
{
  constexpr int SA = (MA == 0) ? 32 : 40;
  constexpr int SB = (MB == 0) ? 32 : 40;
  constexpr int ASZ = 128*SA, BSZ = 128*SB;
  constexpr int DB = 2*ASZ + 2*BSZ;
  constexpr int SMEM = (EPI >= 1 && DB < 128*136) ? 128*136 : DB;
  __shared__ _Float16 smem[SMEM];

  // XCD-chunked mapping: bid%8 = XCD; each XCD owns 2 consecutive batches
  constexpr int TILES = 16*TY;
  const int bid = blockIdx.x;
  const int xcd = bid & 7, slot = bid >> 3;
  const int b = xcd*2 + slot/TILES;
  const int tile = slot % TILES;
  const int by = tile % TY, bx = tile / TY;   // by-fast: B-panel reuse within XCD
  const int row0 = bx*128, col0 = by*128;

  const int t = threadIdx.x, w = t >> 6, l = t & 63;
  const int wr = w >> 1, wc = w & 1, l15 = l & 15, lg = l >> 4;

  const void* Ab;
  const void* Bb;
  if constexpr (MA == 1) Ab = (const void*)((const float*)Ap + (long)b*sA);
  else                   Ab = (const void*)((const _Float16*)Ap + (long)b*sA);
  if constexpr (MB == 1) Bb = (const void*)((const float*)Bp + (long)b*sB);
  else                   Bb = (const void*)((const _Float16*)Bp + (long)b*sB);

  fx4 acc[4][4];
  #pragma unroll
  for (int fi = 0; fi < 4; ++fi)
    #pragma unroll
    for (int fj = 0; fj < 4; ++fj)
      acc[fi][fj] = (fx4){0.f, 0.f, 0.f, 0.f};

  const int NT = K/32;
  fx4 regA[4], regB[4];

  // prologue: tile 0 into buffer 0
  if constexpr (MA == 0)      stage_gld((const _Float16*)Ab, lda, row0, 0, smem, t);
  else                        load_f32((const float*)Ab, lda, row0, 0, t, regA);
  if constexpr (MB == 0)      stage_gld((const _Float16*)Bb, ldb, col0, 0, smem + 2*ASZ, t);
  else                        load_f32((const float*)Bb, ldb, col0, 0, t, regB);
  if constexpr (MA == 1)      write_cvt<SA>(regA, smem, t);
  if constexpr (MB == 1)      write_cvt<SB>(regB, smem + 2*ASZ, t);
  __syncthreads();

  for (int kt = 0; kt < NT; ++kt) {
    const int cur = kt & 1, nxt = cur ^ 1;
    const int k1 = (kt + 1)*32;
    _Float16* cA = smem + cur*ASZ;
    _Float16* cB = smem + 2*ASZ + cur*BSZ;
    _Float16* nA = smem + nxt*ASZ;
    _Float16* nB = smem + 2*ASZ + nxt*BSZ;

    if (kt + 1 < NT) {
      if constexpr (MA == 0)      stage_gld((const _Float16*)Ab, lda, row0, k1, nA, t);
      else                        load_f32((const float*)Ab, lda, row0, k1, t, regA);
      if constexpr (MB == 0)      stage_gld((const _Float16*)Bb, ldb, col0, k1, nB, t);
      else                        load_f32((const float*)Bb, ldb, col0, k1, t, regB);
    }

    h8 af[4], bf[4];
    #pragma unroll
    for (int fi = 0; fi < 4; ++fi)
      af[fi] = *(const h8*)(cA + (wr*64 + fi*16 + l15)*SA + lg*8);
    #pragma unroll
    for (int fj = 0; fj < 4; ++fj)
      bf[fj] = *(const h8*)(cB + (wc*64 + fj*16 + l15)*SB + lg*8);
    #pragma unroll
    for (int fi = 0; fi < 4; ++fi)
      #pragma unroll
      for (int fj = 0; fj < 4; ++fj)
        acc[fi][fj] = __builtin_amdgcn_mfma_f32_16x16x32_f16(af[fi], bf[fj], acc[fi][fj], 0, 0, 0);

    if (kt + 1 < NT) {
      if constexpr (MA == 1) write_cvt<SA>(regA, nA, t);
      if constexpr (MB == 1) write_cvt<SB>(regB, nB, t);
    }
    __syncthreads();
  }

  if constexpr (EPI >= 1) {
    if constexpr (EPI == 1) {
      // round acc to f16 precision (stored Lh/Lt and the softmax stats stay consistent)
      #pragma unroll
      for (int fi = 0; fi < 4; ++fi)
        #pragma unroll
        for (int fj = 0; fj < 4; ++fj)
          #pragma unroll
          for (int j = 0; j < 4; ++j)
            acc[fi][fj][j] = (float)(_Float16)acc[fi][fj][j];
    }

    // swizzled LDS image: (r,c) -> r*136 + (((c>>3) ^ ((r>>3)&7))<<3 | (c&7))
    #pragma unroll
    for (int fi = 0; fi < 4; ++fi) {
      #pragma unroll
      for (int j = 0; j < 4; ++j) {
        int rr = wr*64 + fi*16 + lg*4 + j;
        int key = (rr >> 3) & 7;
        #pragma unroll
        for (int fj = 0; fj < 4; ++fj) {
          int cc = wc*64 + fj*16 + l15;
          smem[rr*136 + ((((cc >> 3) ^ key) << 3) | (cc & 7))] = (_Float16)acc[fi][fj][j];
        }
      }
    }
    __syncthreads();
    _Float16* Cb  = (_Float16*)Cp  + (long)b*sC;
    _Float16* C2b = (_Float16*)C2p + (long)b*sC2;
    // row-major store: read swizzled group
    #pragma unroll
    for (int rd = 0; rd < 8; ++rd) {
      int r = rd*16 + (t >> 4);
      int g = (t & 15) ^ ((r >> 3) & 7);
      h8 v = *(const h8*)(smem + r*136 + g*8);
      *(h8*)(Cb + (long)(row0 + r)*ldc + col0 + (t & 15)*8) = v;
    }
    // transposed store: gather column dl over rows 8q..8q+7 (lane-static key = q&7)
    {
      const int q = t & 15, keyq = q & 7, n8 = q*8;
      #pragma unroll
      for (int rd = 0; rd < 8; ++rd) {
        int dl = rd*16 + (t >> 4);
        int gbase = ((dl >> 3) ^ keyq) << 3, c7 = dl & 7;
        h8 v;
        #pragma unroll
        for (int i = 0; i < 8; ++i)
          v[i] = smem[(n8 + i)*136 + gbase + c7];
        *(h8*)(C2b + (long)(col0 + dl)*ldc2 + row0 + n8) = v;
      }
    }
  }

  if constexpr (EPI == 1) {
    // row partials over this wave's 64-col half
    float rm[4][4], rs[4][4];
    #pragma unroll
    for (int fi = 0; fi < 4; ++fi)
      #pragma unroll
      for (int j = 0; j < 4; ++j)
        rm[fi][j] = fmaxf(fmaxf(acc[fi][0][j], acc[fi][1][j]),
                          fmaxf(acc[fi][2][j], acc[fi][3][j]));
    #pragma unroll
    for (int m = 1; m < 16; m <<= 1)
      #pragma unroll
      for (int fi = 0; fi < 4; ++fi)
        #pragma unroll
        for (int j = 0; j < 4; ++j)
          rm[fi][j] = fmaxf(rm[fi][j], __shfl_xor(rm[fi][j], m, 64));
    #pragma unroll
    for (int fi = 0; fi < 4; ++fi)
      #pragma unroll
      for (int j = 0; j < 4; ++j) {
        float s = 0.f;
        #pragma unroll
        for (int fj = 0; fj < 4; ++fj)
          s += __expf(acc[fi][fj][j] - rm[fi][j]);
        rs[fi][j] = s;
      }
    #pragma unroll
    for (int m = 1; m < 16; m <<= 1)
      #pragma unroll
      for (int fi = 0; fi < 4; ++fi)
        #pragma unroll
        for (int j = 0; j < 4; ++j)
          rs[fi][j] += __shfl_xor(rs[fi][j], m, 64);
    if (l15 == 0) {
      #pragma unroll
      for (int fi = 0; fi < 4; ++fi)
        #pragma unroll
        for (int j = 0; j < 4; ++j) {
          int row = row0 + wr*64 + fi*16 + lg*4 + j;
          long idx = ((long)b*Nn + row)*32 + by*2 + wc;
          rowPM[idx] = rm[fi][j];
          rowPS[idx] = rs[fi][j];
        }
    }
    // col partials over this wave's 64-row half
    float cm[4], cs[4];
    #pragma unroll
    for (int fj = 0; fj < 4; ++fj) {
      float v = -3.4e38f;
      #pragma unroll
      for (int fi = 0; fi < 4; ++fi)
        #pragma unroll
        for (int j = 0; j < 4; ++j)
          v = fmaxf(v, acc[fi][fj][j]);
      cm[fj] = v;
    }
    #pragma unroll
    for (int fj = 0; fj < 4; ++fj) {
      cm[fj] = fmaxf(cm[fj], __shfl_xor(cm[fj], 16, 64));
      cm[fj] = fmaxf(cm[fj], __shfl_xor(cm[fj], 32, 64));
    }
    #pragma unroll
    for (int fj = 0; fj < 4; ++fj) {
      float s = 0.f;
      #pragma unroll
      for (int fi = 0; fi < 4; ++fi)
        #pragma unroll
        for (int j = 0; j < 4; ++j)
          s += __expf(acc[fi][fj][j] - cm[fj]);
      cs[fj] = s;
    }
    #pragma unroll
    for (int fj = 0; fj < 4; ++fj) {
      cs[fj] += __shfl_xor(cs[fj], 16, 64);
      cs[fj] += __shfl_xor(cs[fj], 32, 64);
    }
    if (l < 16) {
      #pragma unroll
      for (int fj = 0; fj < 4; ++fj) {
        int col = col0 + wc*64 + fj*16 + l15;
        long idx = ((long)b*Nn + col)*32 + bx*2 + wr;
        colPM[idx] = cm[fj];
        colPS[idx] = cs[fj];
      }
    }
  }
}

// ---------------- K4/K6: exp-weight GEMM, 128x256 tile + fused f32 softmax output ----------
// C[i][j] = sum_k exp(A[i][k]-kofs[k]) * B[j][k].  A: f16 [2048][2048], B: f16 [512][2048].
// Additionally writes Ofull[i][k] = exp(A[i][k]-oofs[i]) (f32, coalesced) from the same
// staged registers; k-tiles split by parity between the by=0/by=1 block pair -> each
// element written exactly once, no extra reads. This replaces the finalize_AQ pass.
__global__ __launch_bounds__(256, 2) void gemm_expw(
    const _Float16* __restrict__ Ap, const _Float16* __restrict__ Bp,
    float* __restrict__ Cp, const float* __restrict__ kofs,
    float* __restrict__ Ofull, const float* __restrict__ oofs)
{
  constexpr int SA = 40;
  constexpr int ASZ = 128*SA;       // f16 elems
  constexpr int BSZ = 256*32;
  __shared__ _Float16 smem[2*ASZ + 2*BSZ];   // 52 KB

  // XCD-chunked: 512 blocks; xcd = bid&7 owns 2 batches; 32 tiles/batch, by-fast
  const int bid = blockIdx.x;
  const int xcd = bid & 7, slot = bid >> 3;
  const int b = xcd*2 + (slot >> 5);
  const int tile = slot & 31;
  const int by = tile & 1, bx = tile >> 1;
  const int row0 = bx*128, col0 = by*256;

  const int t = threadIdx.x, w = t >> 6, l = t & 63;
  const int wr = w >> 1, wc = w & 1, l15 = l & 15, lg = l >> 4;

  const _Float16* Ab = Ap + (long)b*Nn*Nn;
  const _Float16* Bb = Bp + (long)b*Dn*Nn;
  const float* ko = kofs + (long)b*Nn;
  float* Ob = Ofull + (long)b*Nn*Nn;
  const float ro0 = oofs[(long)b*Nn + row0 + (t >> 2)];
  const float ro1 = oofs[(long)b*Nn + row0 + 64 + (t >> 2)];

  fx4 acc[4][8];
  #pragma unroll
  for (int fi = 0; fi < 4; ++fi)
    #pragma unroll
    for (int fj = 0; fj < 8; ++fj)
      acc[fi][fj] = (fx4){0.f, 0.f, 0.f, 0.f};

  const int NT = Nn/32;
  RegsA3 rA3;

  // prologue (tile 0: written by by==0 blocks)
  load_A3(Ab, Nn, row0, 0, t, ko, rA3);
  stage_gld256(Bb, Nn, col0, 0, smem + 2*ASZ, t);
  write_A3<SA>(rA3, smem, t);
  if (by == 0) write_Of32(rA3, Ob, Nn, row0, 0, t, ro0, ro1);
  __syncthreads();

  for (int kt = 0; kt < NT; ++kt) {
    const int cur = kt & 1, nxt = cur ^ 1;
    const int k1 = (kt + 1)*32;
    _Float16* cA = smem + cur*ASZ;
    _Float16* cB = smem + 2*ASZ + cur*BSZ;
    _Float16* nA = smem + nxt*ASZ;
    _Float16* nB = smem + 2*ASZ + nxt*BSZ;

    if (kt + 1 < NT) {
      load_A3(Ab, Nn, row0, k1, t, ko, rA3);
      stage_gld256(Bb, Nn, col0, k1, nB, t);
    }

    h8 af[4], bf[8];
    #pragma unroll
    for (int fi = 0; fi < 4; ++fi)
      af[fi] = *(const h8*)(cA + (wr*64 + fi*16 + l15)*SA + lg*8);
    #pragma unroll
    for (int fj = 0; fj < 8; ++fj)
      bf[fj] = *(const h8*)(cB + (wc*128 + fj*16 + l15)*32 + lg*8);
    #pragma unroll
    for (int fi = 0; fi < 4; ++fi)
      #pragma unroll
      for (int fj = 0; fj < 8; ++fj)
        acc[fi][fj] = __builtin_amdgcn_mfma_f32_16x16x32_f16(af[fi], bf[fj], acc[fi][fj], 0, 0, 0);

    if (kt + 1 < NT) {
      write_A3<SA>(rA3, nA, t);
      if (((kt + 1) & 1) == by) write_Of32(rA3, Ob, Nn, row0, k1, t, ro0, ro1);
    }
    __syncthreads();
  }

  float* Cb = Cp + (long)b*Nn*Dn;
  #pragma unroll
  for (int fi = 0; fi < 4; ++fi)
    #pragma unroll
    for (int fj = 0; fj < 8; ++fj)
      #pragma unroll
      for (int j = 0; j < 4; ++j)
        Cb[(long)(row0 + wr*64 + fi*16 + lg*4 + j)*Dn + col0 + wc*128 + fj*16 + l15] = acc[fi][fj][j];
}

// ---------------- x2 f32 -> x2h f16 + x2hT f16 ----------------
__global__ __launch_bounds__(256) void convert_x2(const float* __restrict__ x2,
    _Float16* __restrict__ x2h, _Float16* __restrict__ x2hT)
{
  __shared__ _Float16 lt[64*66];
  const int b = blockIdx.z, m0 = blockIdx.x*64, d0 = blockIdx.y*64;
  const int t = threadIdx.x;
  const float* xb = x2 + (long)b*Nn*Dn;
  _Float16* hb = x2h + (long)b*Nn*Dn;
  #pragma unroll
  for (int rd = 0; rd < 4; ++rd) {
    int r = rd*16 + (t >> 4), c = (t & 15)*4;
    fx4 v = *(const fx4*)(xb + (long)(m0 + r)*Dn + d0 + c);
    h4 h;
    #pragma unroll
    for (int i = 0; i < 4; ++i) { h[i] = (_Float16)v[i]; lt[r*66 + c + i] = h[i]; }
    *(h4*)(hb + (long)(m0 + r)*Dn + d0 + c) = h;
  }
  __syncthreads();
  _Float16* tb = x2hT + (long)b*Dn*Nn;
  #pragma unroll
  for (int rd = 0; rd < 4; ++rd) {
    int dl = rd*16 + (t >> 4), ml = (t & 15)*4;
    h4 h;
    #pragma unroll
    for (int i = 0; i < 4; ++i) h[i] = lt[(ml + i)*66 + dl];
    *(h4*)(tb + (long)(d0 + dl)*Nn + m0 + ml) = h;
  }
}

// ---------------- combine 32 partials per row/col -> ofs = max + log(sum) ----------------
__global__ __launch_bounds__(256) void reduce_stats(
    const float* __restrict__ rowPM, const float* __restrict__ rowPS,
    const float* __restrict__ colPM, const float* __restrict__ colPS,
    float* __restrict__ rofs, float* __restrict__ cofs)
{
  const int w = threadIdx.x >> 6, l = threadIdx.x & 63;
  const long row = (long)blockIdx.x*4 + w;
  const float* PM = blockIdx.y ? colPM : rowPM;
  const float* PS = blockIdx.y ? colPS : rowPS;
  float m0 = PM[row*32 + (l & 31)];
  float s0 = PS[row*32 + (l & 31)];
  float m = m0;
  #pragma unroll
  for (int k = 1; k < 32; k <<= 1) m = fmaxf(m, __shfl_xor(m, k, 64));
  float v = s0 * __expf(m0 - m);
  #pragma unroll
  for (int k = 1; k < 32; k <<= 1) v += __shfl_xor(v, k, 64);
  if (l == 0) {
    float ofs = m + __logf(v);
    if (blockIdx.y == 0) rofs[row] = ofs;
    else                 cofs[row] = ofs;
  }
}

} // namespace

extern "C" void kernel_launch(void* const* d_in, const int* in_sizes, int n_in,
                              void* d_out, int out_size, void* d_ws, size_t ws_size,
                              hipStream_t stream)
{
  const float* x1 = (const float*)d_in[0];
  const float* x2 = (const float*)d_in[1];
  // d_in[2] = node_mask: unused by reference
  const float* Wq = (const float*)d_in[3];

  float* out = (float*)d_out;
  float* C_Q = out;
  float* C_D = out + (long)Bn*Nn*Dn;
  float* A_D = out + 2L*Bn*Nn*Dn;
  float* A_Q = A_D + (long)Bn*Nn*Nn;

  // ws: Qh, QhT, x2h, x2hT (f16) + Lh (f16) + stats
  char* ws = (char*)d_ws;
  _Float16* Qh   = (_Float16*)ws;
  _Float16* QhT  = Qh   + (long)Bn*Nn*Dn;
  _Float16* x2h  = QhT  + (long)Bn*Dn*Nn;
  _Float16* x2hT = x2h  + (long)Bn*Nn*Dn;
  _Float16* Lh   = x2hT + (long)Bn*Dn*Nn;
  float* rofs = (float*)(Lh + (long)Bn*Nn*Nn);
  float* cofs = rofs + (long)Bn*Nn;

  // scratch aliased into the A_D output region (serialized: Lt+partials -> K6 reads Lt
  // -> K4's fused A_D writes overwrite the whole region). A_Q untouched until K6 writes it.
  _Float16* Lt = (_Float16*)A_D;                                      // 134 MB
  float* rowPM = (float*)((char*)A_D + sizeof(_Float16)*(long)Bn*Nn*Nn);
  float* rowPS = rowPM + (long)Bn*Nn*32;
  float* colPM = rowPS + (long)Bn*Nn*32;
  float* colPS = colPM + (long)Bn*Nn*32;

  dim3 blk(256);

  // K0: x2 -> f16 + transposed
  convert_x2<<<dim3(32, 8, 16), blk, 0, stream>>>(x2, x2h, x2hT);

  // K1: Q = x1 @ Wq^T -> Qh + QhT (f16). B = Wq shared across batches (sB = 0).
  gemm128<1,1,2,4><<<dim3(1024), blk, 0, stream>>>(
      x1, (long)Nn*Dn, Wq, 0L,
      Qh, (long)Nn*Dn, Dn, QhT, (long)Dn*Nn, Nn,
      Dn, Dn, Dn,
      nullptr, nullptr, nullptr, nullptr);

  // K2: Lh + Lt = (f16)(Qh @ x2h^T) dual-store + fused softmax partials
  gemm128<0,0,1,16><<<dim3(4096), blk, 0, stream>>>(
      Qh, (long)Nn*Dn, x2h, (long)Nn*Dn,
      Lh, (long)Nn*Nn, Nn, Lt, (long)Nn*Nn, Nn,
      Dn, Dn, Dn,
      rowPM, rowPS, colPM, colPS);

  // K3: combine partials -> rofs/cofs = max + log(sum)
  reduce_stats<<<dim3(Bn*Nn/4, 2), blk, 0, stream>>>(rowPM, rowPS, colPM, colPS, rofs, cofs);

  // K6 (first!): C_D = rowsoftmax(L)^T @ Q from Lt; fused A_Q[m][n] = exp(Lt[m][n]-cofs[m])
  gemm_expw<<<dim3(512), blk, 0, stream>>>(Lt, QhT, C_D, rofs, A_Q, cofs);

  // K4: C_Q = colsoftmax(L) @ x2 from Lh; fused A_D[n][m] = exp(Lh[n][m]-rofs[n])
  // (overwrites the Lt/partials scratch in the A_D region — K6/K3 already consumed them)
  gemm_expw<<<dim3(512), blk, 0, stream>>>(Lh, x2hT, C_Q, cofs, A_D, rofs);
}